// Round 5
// baseline (151.113 us; speedup 1.0000x reference)
//
#include <hip/hip_runtime.h>
#include <hip/hip_bf16.h>

// b=2, L=1024, d=1024, dt_rank=64, n=16, E=96
#define LSEQ 1024
#define DMODEL 1024
#define NSTATE 16
#define DTRANK 64
#define ECOL 96
#define MTOT 2048

typedef short s16x8 __attribute__((ext_vector_type(8)));
typedef float f32x4 __attribute__((ext_vector_type(4)));

__device__ inline unsigned short f2bf(float f) {
    unsigned int u = __builtin_bit_cast(unsigned int, f);
    u += 0x7FFFu + ((u >> 16) & 1u);
    return (unsigned short)(u >> 16);
}
__device__ inline float bf2f(unsigned short h) {
    unsigned int u = ((unsigned int)h) << 16;
    return __builtin_bit_cast(float, u);
}

__device__ inline f32x4 shflup4(f32x4 v, int off) {
    f32x4 r;
    r[0] = __shfl_up(v[0], off, 64);
    r[1] = __shfl_up(v[1], off, 64);
    r[2] = __shfl_up(v[2], off, 64);
    r[3] = __shfl_up(v[3], off, 64);
    return r;
}

// ---------------- split x -> xh, xl (bf16 two-term split, [m][k]) ----------------
__global__ __launch_bounds__(256) void k_splitx(const float* __restrict__ x,
                                                unsigned short* __restrict__ xh,
                                                unsigned short* __restrict__ xl) {
    size_t i = ((size_t)blockIdx.x * 256 + threadIdx.x) * 8;
    float4 v0 = *reinterpret_cast<const float4*>(&x[i]);
    float4 v1 = *reinterpret_cast<const float4*>(&x[i + 4]);
    float v[8] = {v0.x, v0.y, v0.z, v0.w, v1.x, v1.y, v1.z, v1.w};
    s16x8 h, l;
#pragma unroll
    for (int j = 0; j < 8; ++j) {
        unsigned short hb = f2bf(v[j]);
        h[j] = (short)hb;
        l[j] = (short)f2bf(v[j] - bf2f(hb));
    }
    *reinterpret_cast<s16x8*>(&xh[i]) = h;
    *reinterpret_cast<s16x8*>(&xl[i]) = l;
}

// ---------------- Wx [1024][96] -> WxT hi/lo [96][1024] ----------------
__global__ __launch_bounds__(256) void k_wxT(const float* __restrict__ Wx,
                                             unsigned short* __restrict__ WxTh,
                                             unsigned short* __restrict__ WxTl) {
    __shared__ float t[32][33];
    int e0 = blockIdx.x * 32, k0 = blockIdx.y * 32;
    int tx = threadIdx.x & 31, ty = threadIdx.x >> 5;
#pragma unroll
    for (int j = 0; j < 32; j += 8)
        t[ty + j][tx] = Wx[(size_t)(k0 + ty + j) * 96 + e0 + tx];
    __syncthreads();
#pragma unroll
    for (int j = 0; j < 32; j += 8) {
        float v = t[tx][ty + j];
        unsigned short h = f2bf(v);
        WxTh[(size_t)(e0 + ty + j) * 1024 + k0 + tx] = h;
        WxTl[(size_t)(e0 + ty + j) * 1024 + k0 + tx] = f2bf(v - bf2f(h));
    }
}

// ---------------- Wdt [64][1024] -> WdtT hi/lo [1024][64] ----------------
__global__ __launch_bounds__(256) void k_wdtT(const float* __restrict__ Wdt,
                                              unsigned short* __restrict__ WdtTh,
                                              unsigned short* __restrict__ WdtTl) {
    __shared__ float t[32][33];
    int d0 = blockIdx.x * 32, r0 = blockIdx.y * 32;
    int tx = threadIdx.x & 31, ty = threadIdx.x >> 5;
#pragma unroll
    for (int j = 0; j < 32; j += 8)
        t[ty + j][tx] = Wdt[(size_t)(r0 + ty + j) * 1024 + d0 + tx];
    __syncthreads();
#pragma unroll
    for (int j = 0; j < 32; j += 8) {
        float v = t[tx][ty + j];
        unsigned short h = f2bf(v);
        WdtTh[(size_t)(d0 + ty + j) * 64 + r0 + tx] = h;
        WdtTl[(size_t)(d0 + ty + j) * 64 + r0 + tx] = f2bf(v - bf2f(h));
    }
}

// ---------------- Transpose x [2048][1024] -> xT [1024][2048] ----------------
__global__ __launch_bounds__(256) void k_transp(const float* __restrict__ in,
                                                float* __restrict__ out) {
    __shared__ float tile[32][33];
    int x0 = blockIdx.x * 32;  // d
    int y0 = blockIdx.y * 32;  // m
    int tx = threadIdx.x & 31, ty = threadIdx.x >> 5;
#pragma unroll
    for (int j = 0; j < 32; j += 8)
        tile[ty + j][tx] = in[(size_t)(y0 + ty + j) * 1024 + x0 + tx];
    __syncthreads();
#pragma unroll
    for (int j = 0; j < 32; j += 8)
        out[(size_t)(x0 + ty + j) * 2048 + y0 + tx] = tile[tx][ty + j];
}

// ---------------- xdbl via MFMA split: M=2048 N=96 K=1024 ----------------
// emits delta cols as bf16 hi/lo [m][64] and packed B/C fp32 [m][16]
__global__ __launch_bounds__(256) void k_xdbl2(const unsigned short* __restrict__ xh,
                                               const unsigned short* __restrict__ xl,
                                               const unsigned short* __restrict__ WxTh,
                                               const unsigned short* __restrict__ WxTl,
                                               unsigned short* __restrict__ xdh,
                                               unsigned short* __restrict__ xdl,
                                               float* __restrict__ bpk,
                                               float* __restrict__ cpk) {
    __shared__ float sacc[64][100];
    int bm = blockIdx.x * 64;
    int tid = threadIdx.x, lane = tid & 63, w = tid >> 6;
    int r = lane & 15, kb = lane >> 4;

    f32x4 acc[6];
#pragma unroll
    for (int nf = 0; nf < 6; ++nf) acc[nf] = (f32x4){0.f, 0.f, 0.f, 0.f};

    s16x8 ah[2], al[2], bh[2][6], bl[2][6];
    const size_t arow = (size_t)(bm + w * 16 + r) * 1024 + kb * 8;
    auto xdload = [&](int k0, int p) {
        ah[p] = *(const s16x8*)&xh[arow + k0];
        al[p] = *(const s16x8*)&xl[arow + k0];
#pragma unroll
        for (int nf = 0; nf < 6; ++nf) {
            size_t brow = (size_t)(nf * 16 + r) * 1024 + k0 + kb * 8;
            bh[p][nf] = *(const s16x8*)&WxTh[brow];
            bl[p][nf] = *(const s16x8*)&WxTl[brow];
        }
    };
    auto xdmfma = [&](int p) {
#pragma unroll
        for (int nf = 0; nf < 6; ++nf) {
            acc[nf] = __builtin_amdgcn_mfma_f32_16x16x32_bf16(ah[p], bh[p][nf], acc[nf], 0, 0, 0);
            acc[nf] = __builtin_amdgcn_mfma_f32_16x16x32_bf16(ah[p], bl[p][nf], acc[nf], 0, 0, 0);
            acc[nf] = __builtin_amdgcn_mfma_f32_16x16x32_bf16(al[p], bh[p][nf], acc[nf], 0, 0, 0);
        }
    };
    xdload(0, 0);
#pragma unroll 1
    for (int k0 = 0; k0 < 1024; k0 += 64) {
        xdload(k0 + 32, 1);
        xdmfma(0);
        xdload((k0 + 64) & 1023, 0);
        xdmfma(1);
    }

#pragma unroll
    for (int nf = 0; nf < 6; ++nf)
#pragma unroll
        for (int j = 0; j < 4; ++j)
            sacc[w * 16 + kb * 4 + j][nf * 16 + r] = acc[nf][j];
    __syncthreads();

    // delta cols 0..63 -> bf16 hi/lo split
    {
        int m = tid >> 2;
        int c0 = (tid & 3) * 16;
#pragma unroll
        for (int q = 0; q < 2; ++q) {
            s16x8 hv, lv;
#pragma unroll
            for (int i = 0; i < 8; ++i) {
                float v = sacc[m][c0 + q * 8 + i];
                unsigned short h = f2bf(v);
                hv[i] = (short)h;
                lv[i] = (short)f2bf(v - bf2f(h));
            }
            *(s16x8*)&xdh[(size_t)(bm + m) * 64 + c0 + q * 8] = hv;
            *(s16x8*)&xdl[(size_t)(bm + m) * 64 + c0 + q * 8] = lv;
        }
    }
    // B (cols 64..79) and C (cols 80..95) packed fp32
    {
        int mm = tid & 63, g = tid >> 6;
        f32x4 bv = *(const f32x4*)&sacc[mm][64 + g * 4];
        f32x4 cv = *(const f32x4*)&sacc[mm][80 + g * 4];
        *(f32x4*)&bpk[(size_t)(bm + mm) * 16 + g * 4] = bv;
        *(f32x4*)&cpk[(size_t)(bm + mm) * 16 + g * 4] = cv;
    }
}

// ---------------- delta via MFMA split: M=2048 N=1024 K=64 -> softplus -> deltaT [d][m] ----------------
__global__ __launch_bounds__(256) void k_delta2(const unsigned short* __restrict__ xdh,
                                                const unsigned short* __restrict__ xdl,
                                                const unsigned short* __restrict__ WdtTh,
                                                const unsigned short* __restrict__ WdtTl,
                                                const float* __restrict__ bdt,
                                                float* __restrict__ deltaT) {
    __shared__ float slab[4][32][68];
    int bm = blockIdx.y * 128;
    int bn = blockIdx.x * 128;
    int tid = threadIdx.x, lane = tid & 63, w = tid >> 6;
    int wm = w >> 1, wn = w & 1;
    int r = lane & 15, kb = lane >> 4;

    f32x4 acc[4][4];
#pragma unroll
    for (int mf = 0; mf < 4; ++mf)
#pragma unroll
        for (int nf = 0; nf < 4; ++nf) acc[mf][nf] = (f32x4){0.f, 0.f, 0.f, 0.f};

#pragma unroll
    for (int ks = 0; ks < 2; ++ks) {
        s16x8 Ah[4], Al[4], Bh[4], Bl[4];
#pragma unroll
        for (int mf = 0; mf < 4; ++mf) {
            size_t a = (size_t)(bm + wm * 64 + mf * 16 + r) * 64 + ks * 32 + kb * 8;
            Ah[mf] = *(const s16x8*)&xdh[a];
            Al[mf] = *(const s16x8*)&xdl[a];
        }
#pragma unroll
        for (int nf = 0; nf < 4; ++nf) {
            size_t b = (size_t)(bn + wn * 64 + nf * 16 + r) * 64 + ks * 32 + kb * 8;
            Bh[nf] = *(const s16x8*)&WdtTh[b];
            Bl[nf] = *(const s16x8*)&WdtTl[b];
        }
#pragma unroll
        for (int mf = 0; mf < 4; ++mf)
#pragma unroll
            for (int nf = 0; nf < 4; ++nf) {
                acc[mf][nf] = __builtin_amdgcn_mfma_f32_16x16x32_bf16(Ah[mf], Bh[nf], acc[mf][nf], 0, 0, 0);
                acc[mf][nf] = __builtin_amdgcn_mfma_f32_16x16x32_bf16(Ah[mf], Bl[nf], acc[mf][nf], 0, 0, 0);
                acc[mf][nf] = __builtin_amdgcn_mfma_f32_16x16x32_bf16(Al[mf], Bh[nf], acc[mf][nf], 0, 0, 0);
            }
    }

    // epilogue: bias + softplus, per-wave LDS transpose, coalesced [d][m] writes
#pragma unroll
    for (int half = 0; half < 2; ++half) {
#pragma unroll
        for (int nf2 = 0; nf2 < 2; ++nf2) {
            int nf = half * 2 + nf2;
            float bb = bdt[bn + wn * 64 + nf * 16 + r];
#pragma unroll
            for (int mf = 0; mf < 4; ++mf)
#pragma unroll
                for (int j = 0; j < 4; ++j) {
                    float z = acc[mf][nf][j] + bb;
                    float sp = fmaxf(z, 0.f) + log1pf(expf(-fabsf(z)));
                    slab[w][nf2 * 16 + r][mf * 16 + kb * 4 + j] = sp;
                }
        }
        // wave-private slab: ds ordering within the wave is program-order
#pragma unroll
        for (int i = 0; i < 8; ++i) {
            int idx = i * 64 + lane;
            int dl = idx >> 4, mq = (idx & 15) * 4;
            f32x4 v = *(const f32x4*)&slab[w][dl][mq];
            *(f32x4*)&deltaT[(size_t)(bn + wn * 64 + half * 32 + dl) * MTOT + bm + wm * 64 + mq] = v;
        }
    }
}

// ---------------- Kernel C: chunked selective scan -> yT bf16 [d][m] ----------------
__global__ __launch_bounds__(256) void k_scan3(const float* __restrict__ deltaT,
                                               const float* __restrict__ xT,
                                               const float* __restrict__ bpk,
                                               const float* __restrict__ cpk,
                                               const float* __restrict__ Alog,
                                               const float* __restrict__ Dp,
                                               unsigned short* __restrict__ yTbf) {
    __shared__ double csum[64];
    __shared__ double Rbef[64];
    __shared__ float TcL[64 * 20];
    __shared__ float syp[64 * 17];

    int tid = threadIdx.x;
    int c = tid >> 2, l = tid & 3;
    int w = tid >> 6, lane = tid & 63;
    int d = blockIdx.x & 1023, b = blockIdx.x >> 10;
    int m0 = b * 1024;

    const f32x4* dp = (const f32x4*)(deltaT + (size_t)d * MTOT + m0 + c * 16);
    const f32x4* up = (const f32x4*)(xT + (size_t)d * MTOT + m0 + c * 16);
    const f32x4* Bp = (const f32x4*)bpk + (size_t)(m0 + c * 16) * 4 + l;
    const f32x4* Cp = (const f32x4*)cpk + (size_t)(m0 + c * 16) * 4 + l;

    double dsum = 0.0;
#pragma unroll
    for (int i = 0; i < 4; ++i) {
        f32x4 v = dp[i];
        dsum += (double)v[0] + (double)v[1] + (double)v[2] + (double)v[3];
    }
    if (l == 0) csum[c] = dsum;
    __syncthreads();
    if (tid < 64) {
        double v = csum[tid];
#pragma unroll
        for (int off = 1; off < 64; off <<= 1) {
            double t = __shfl_down(v, off, 64);
            if (tid + off < 64) v += t;
        }
        Rbef[tid] = v;
    }
    __syncthreads();

    float Af[4], Sb[4];
    double Rb = Rbef[c];
#pragma unroll
    for (int j = 0; j < 4; ++j) {
        Af[j] = -__expf(Alog[d * NSTATE + 4 * l + j]);
        Sb[j] = (float)((double)Af[j] * Rb);
    }
    float Dv = Dp[d];

    float P = 0.f;
    f32x4 Tn = {0.f, 0.f, 0.f, 0.f};
#pragma unroll 1
    for (int t4 = 0; t4 < 4; ++t4) {
        f32x4 rdv = dp[t4];
        f32x4 ruv = up[t4];
        f32x4 Bq0 = Bp[(t4 * 4 + 0) * 4];
        f32x4 Bq1 = Bp[(t4 * 4 + 1) * 4];
        f32x4 Bq2 = Bp[(t4 * 4 + 2) * 4];
        f32x4 Bq3 = Bp[(t4 * 4 + 3) * 4];
        f32x4 Bq[4] = {Bq0, Bq1, Bq2, Bq3};
#pragma unroll
        for (int k = 0; k < 4; ++k) {
            float dlt = rdv[k];
            P += dlt;
            float du = dlt * ruv[k];
#pragma unroll
            for (int j = 0; j < 4; ++j) {
                float e = __expf(fmaf(-Af[j], P, Sb[j]));
                Tn[j] = fmaf(du * Bq[k][j], e, Tn[j]);
            }
        }
    }
    *(f32x4*)&TcL[c * 20 + 4 * l] = Tn;
    __syncthreads();

    {
        f32x4 v = *(const f32x4*)&TcL[lane * 20 + 4 * w];
#pragma unroll
        for (int off = 1; off < 64; off <<= 1) {
            f32x4 t = shflup4(v, off);
            if (lane >= off) v += t;
        }
        f32x4 ex = shflup4(v, 1);
        if (lane == 0) ex = (f32x4){0.f, 0.f, 0.f, 0.f};
        *(f32x4*)&TcL[lane * 20 + 4 * w] = ex;
    }
    __syncthreads();
    f32x4 num = *(const f32x4*)&TcL[c * 20 + 4 * l];

    P = 0.f;
#pragma unroll 1
    for (int t4 = 0; t4 < 4; ++t4) {
        f32x4 rdv = dp[t4];
        f32x4 ruv = up[t4];
        f32x4 Bq[4], Cq[4];
#pragma unroll
        for (int k = 0; k < 4; ++k) {
            Bq[k] = Bp[(t4 * 4 + k) * 4];
            Cq[k] = Cp[(t4 * 4 + k) * 4];
        }
#pragma unroll
        for (int k = 0; k < 4; ++k) {
            float dlt = rdv[k];
            P += dlt;
            float du = dlt * ruv[k];
            float psum = 0.f;
#pragma unroll
            for (int j = 0; j < 4; ++j) {
                float e = __expf(fmaf(-Af[j], P, Sb[j]));
                num[j] = fmaf(du * Bq[k][j], e, num[j]);
                float rr = __builtin_amdgcn_rcpf(e + 1e-12f);
                psum = fmaf(num[j] * rr, Cq[k][j], psum);
            }
            psum += __shfl_xor(psum, 1);
            psum += __shfl_xor(psum, 2);
            if (l == 0) syp[c * 17 + t4 * 4 + k] = fmaf(ruv[k], Dv, psum);
        }
    }
    __syncthreads();
    {
        int cc = tid >> 2, oo = (tid & 3) * 4;
        const float* sp = &syp[cc * 17 + oo];
        ushort4 o;
        o.x = f2bf(sp[0]);
        o.y = f2bf(sp[1]);
        o.z = f2bf(sp[2]);
        o.w = f2bf(sp[3]);
        *reinterpret_cast<ushort4*>(&yTbf[(size_t)d * MTOT + m0 + tid * 4]) = o;
    }
}

// ---------------- W_out [k][e] f32 -> WbfT [e][k] bf16 ----------------
__global__ __launch_bounds__(256) void k_wconv(const float* __restrict__ W,
                                               unsigned short* __restrict__ WT) {
    __shared__ float t[64][65];
    int k0 = blockIdx.y * 64, e0 = blockIdx.x * 64;
    int tx = threadIdx.x & 63, ty = threadIdx.x >> 6;
#pragma unroll
    for (int j = 0; j < 64; j += 4)
        t[ty + j][tx] = W[(size_t)(k0 + ty + j) * 1024 + e0 + tx];
    __syncthreads();
#pragma unroll
    for (int j = 0; j < 64; j += 4)
        WT[(size_t)(e0 + ty + j) * 1024 + k0 + tx] = f2bf(t[tx][ty + j]);
}

// ---------------- yTbf [d][m] bf16 -> ybf [m][d] bf16 ----------------
__global__ __launch_bounds__(256) void k_ytr(const unsigned short* __restrict__ in,
                                             unsigned short* __restrict__ out) {
    __shared__ unsigned short t[64][66];
    int d0 = blockIdx.y * 64, m0 = blockIdx.x * 64;
    int tx = threadIdx.x & 63, ty = threadIdx.x >> 6;
#pragma unroll
    for (int j = 0; j < 64; j += 4)
        t[ty + j][tx] = in[(size_t)(d0 + ty + j) * MTOT + m0 + tx];
    __syncthreads();
#pragma unroll
    for (int j = 0; j < 64; j += 4)
        out[(size_t)(m0 + ty + j) * 1024 + d0 + tx] = t[tx][ty + j];
}

// ---------------- Kernel D: out = ybf @ WbfT^T + b_out via MFMA ----------------
__global__ __launch_bounds__(256) void k_gemm(const unsigned short* __restrict__ A,
                                              const unsigned short* __restrict__ B,
                                              const float* __restrict__ bias,
                                              float* __restrict__ out) {
    __shared__ unsigned short As[128 * 64];
    __shared__ unsigned short Bs[64 * 64];
    const int GN = 1024, GK = 1024;
    int bm = blockIdx.y * 128;
    int bn = blockIdx.x * 64;
    int tid = threadIdx.x;
    int lane = tid & 63;
    int w = tid >> 6;
    int wm = w >> 1, wn = w & 1;
    int r = lane & 15, kb = lane >> 4;

    f32x4 zero4 = {0.f, 0.f, 0.f, 0.f};
    f32x4 acc[4][2];
#pragma unroll
    for (int mf = 0; mf < 4; ++mf)
#pragma unroll
        for (int nf = 0; nf < 2; ++nf) acc[mf][nf] = zero4;

    s16x8 ra[4], rb[2];
    auto stage_load = [&](int k0) {
#pragma unroll
        for (int i = 0; i < 4; ++i) {
            int q = tid + i * 256;
            ra[i] = *reinterpret_cast<const s16x8*>(&A[(size_t)(bm + (q >> 3)) * GK + k0 + (q & 7) * 8]);
        }
#pragma unroll
        for (int i = 0; i < 2; ++i) {
            int q = tid + i * 256;
            rb[i] = *reinterpret_cast<const s16x8*>(&B[(size_t)(bn + (q >> 3)) * GK + k0 + (q & 7) * 8]);
        }
    };

    stage_load(0);
    for (int k0 = 0; k0 < GK; k0 += 64) {
        __syncthreads();
#pragma unroll
        for (int i = 0; i < 4; ++i)
            *reinterpret_cast<s16x8*>(&As[(tid + i * 256) * 8]) = ra[i];
#pragma unroll
        for (int i = 0; i < 2; ++i)
            *reinterpret_cast<s16x8*>(&Bs[(tid + i * 256) * 8]) = rb[i];
        __syncthreads();
        if (k0 + 64 < GK) stage_load(k0 + 64);
#pragma unroll
        for (int ks = 0; ks < 2; ++ks) {
            s16x8 af[4], bfr[2];
#pragma unroll
            for (int mf = 0; mf < 4; ++mf)
                af[mf] = *reinterpret_cast<const s16x8*>(&As[(wm * 64 + mf * 16 + r) * 64 + ks * 32 + kb * 8]);
#pragma unroll
            for (int nf = 0; nf < 2; ++nf)
                bfr[nf] = *reinterpret_cast<const s16x8*>(&Bs[(wn * 32 + nf * 16 + r) * 64 + ks * 32 + kb * 8]);
#pragma unroll
            for (int mf = 0; mf < 4; ++mf)
#pragma unroll
                for (int nf = 0; nf < 2; ++nf)
                    acc[mf][nf] = __builtin_amdgcn_mfma_f32_16x16x32_bf16(af[mf], bfr[nf], acc[mf][nf], 0, 0, 0);
        }
    }
#pragma unroll
    for (int nf = 0; nf < 2; ++nf) {
        float bb = bias[bn + wn * 32 + nf * 16 + r];
#pragma unroll
        for (int mf = 0; mf < 4; ++mf)
#pragma unroll
            for (int j = 0; j < 4; ++j)
                out[(size_t)(bm + wm * 64 + mf * 16 + kb * 4 + j) * GN + bn + wn * 32 + nf * 16 + r] =
                    acc[mf][nf][j] + bb;
    }
}

extern "C" void kernel_launch(void* const* d_in, const int* in_sizes, int n_in,
                              void* d_out, int out_size, void* d_ws, size_t ws_size,
                              hipStream_t stream) {
    const float* x    = (const float*)d_in[0];
    const float* Wx   = (const float*)d_in[1];
    const float* Wdt  = (const float*)d_in[2];
    const float* bdt  = (const float*)d_in[3];
    const float* Alog = (const float*)d_in[4];
    const float* Dp   = (const float*)d_in[5];
    const float* Wout = (const float*)d_in[6];
    const float* bout = (const float*)d_in[7];
    float* out = (float*)d_out;

    float* xT     = (float*)d_ws;                          // 1024*2048 f
    float* deltaT = xT + 1024 * 2048;                      // 1024*2048 f
    float* bpk    = deltaT + 1024 * 2048;                  // 2048*16 f
    float* cpk    = bpk + 2048 * 16;                       // 2048*16 f
    unsigned short* xh    = (unsigned short*)(cpk + 2048 * 16);
    unsigned short* xl    = xh + 2048 * 1024;
    unsigned short* WxTh  = xl + 2048 * 1024;              // 96*1024
    unsigned short* WxTl  = WxTh + 96 * 1024;
    unsigned short* WdtTh = WxTl + 96 * 1024;              // 1024*64
    unsigned short* WdtTl = WdtTh + 1024 * 64;
    unsigned short* xdh   = WdtTl + 1024 * 64;             // 2048*64
    unsigned short* xdl   = xdh + 2048 * 64;
    unsigned short* yTbf  = xdl + 2048 * 64;               // 1024*2048
    unsigned short* ybf   = yTbf + 1024 * 2048;            // 2048*1024
    unsigned short* WbfT  = ybf + 2048 * 1024;             // 1024*1024

    k_splitx<<<1024, 256, 0, stream>>>(x, xh, xl);
    k_wxT<<<dim3(3, 32), 256, 0, stream>>>(Wx, WxTh, WxTl);
    k_wdtT<<<dim3(32, 2), 256, 0, stream>>>(Wdt, WdtTh, WdtTl);
    k_wconv<<<dim3(16, 16), 256, 0, stream>>>(Wout, WbfT);
    k_transp<<<dim3(32, 64), 256, 0, stream>>>(x, xT);
    k_xdbl2<<<32, 256, 0, stream>>>(xh, xl, WxTh, WxTl, xdh, xdl, bpk, cpk);
    k_delta2<<<dim3(8, 16), 256, 0, stream>>>(xdh, xdl, WdtTh, WdtTl, bdt, deltaT);
    k_scan3<<<2048, 256, 0, stream>>>(deltaT, xT, bpk, cpk, Alog, Dp, yTbf);
    k_ytr<<<dim3(32, 16), 256, 0, stream>>>(yTbf, ybf);
    k_gemm<<<dim3(16, 16), 256, 0, stream>>>(ybf, WbfT, bout, out);
}

// Round 6
// 92.181 us; speedup vs baseline: 1.6393x; 1.6393x over previous
//
#include <hip/hip_runtime.h>
#include <hip/hip_bf16.h>

// b=2, L=1024, d=1024, dt_rank=64, n=16, E=96
#define LSEQ 1024
#define DMODEL 1024
#define NSTATE 16
#define DTRANK 64
#define ECOL 96
#define MTOT 2048

typedef short s16x8 __attribute__((ext_vector_type(8)));
typedef float f32x4 __attribute__((ext_vector_type(4)));

__device__ inline unsigned short f2bf(float f) {
    unsigned int u = __builtin_bit_cast(unsigned int, f);
    u += 0x7FFFu + ((u >> 16) & 1u);
    return (unsigned short)(u >> 16);
}
__device__ inline float bf2f(unsigned short h) {
    unsigned int u = ((unsigned int)h) << 16;
    return __builtin_bit_cast(float, u);
}

__device__ inline f32x4 shflup4(f32x4 v, int off) {
    f32x4 r;
    r[0] = __shfl_up(v[0], off, 64);
    r[1] = __shfl_up(v[1], off, 64);
    r[2] = __shfl_up(v[2], off, 64);
    r[3] = __shfl_up(v[3], off, 64);
    return r;
}

// ---------------- split x -> xh, xl (bf16 two-term split, [m][k]) ----------------
__global__ __launch_bounds__(256) void k_splitx(const float* __restrict__ x,
                                                unsigned short* __restrict__ xh,
                                                unsigned short* __restrict__ xl) {
    size_t i = ((size_t)blockIdx.x * 256 + threadIdx.x) * 8;
    float4 v0 = *reinterpret_cast<const float4*>(&x[i]);
    float4 v1 = *reinterpret_cast<const float4*>(&x[i + 4]);
    float v[8] = {v0.x, v0.y, v0.z, v0.w, v1.x, v1.y, v1.z, v1.w};
    s16x8 h, l;
#pragma unroll
    for (int j = 0; j < 8; ++j) {
        unsigned short hb = f2bf(v[j]);
        h[j] = (short)hb;
        l[j] = (short)f2bf(v[j] - bf2f(hb));
    }
    *reinterpret_cast<s16x8*>(&xh[i]) = h;
    *reinterpret_cast<s16x8*>(&xl[i]) = l;
}

// ---------------- Wx [1024][96] -> WxT hi/lo [96][1024] ----------------
__global__ __launch_bounds__(256) void k_wxT(const float* __restrict__ Wx,
                                             unsigned short* __restrict__ WxTh,
                                             unsigned short* __restrict__ WxTl) {
    __shared__ float t[32][33];
    int e0 = blockIdx.x * 32, k0 = blockIdx.y * 32;
    int tx = threadIdx.x & 31, ty = threadIdx.x >> 5;
#pragma unroll
    for (int j = 0; j < 32; j += 8)
        t[ty + j][tx] = Wx[(size_t)(k0 + ty + j) * 96 + e0 + tx];
    __syncthreads();
#pragma unroll
    for (int j = 0; j < 32; j += 8) {
        float v = t[tx][ty + j];
        unsigned short h = f2bf(v);
        WxTh[(size_t)(e0 + ty + j) * 1024 + k0 + tx] = h;
        WxTl[(size_t)(e0 + ty + j) * 1024 + k0 + tx] = f2bf(v - bf2f(h));
    }
}

// ---------------- Wdt [64][1024] -> WdtT hi/lo [1024][64] ----------------
__global__ __launch_bounds__(256) void k_wdtT(const float* __restrict__ Wdt,
                                              unsigned short* __restrict__ WdtTh,
                                              unsigned short* __restrict__ WdtTl) {
    __shared__ float t[32][33];
    int d0 = blockIdx.x * 32, r0 = blockIdx.y * 32;
    int tx = threadIdx.x & 31, ty = threadIdx.x >> 5;
#pragma unroll
    for (int j = 0; j < 32; j += 8)
        t[ty + j][tx] = Wdt[(size_t)(r0 + ty + j) * 1024 + d0 + tx];
    __syncthreads();
#pragma unroll
    for (int j = 0; j < 32; j += 8) {
        float v = t[tx][ty + j];
        unsigned short h = f2bf(v);
        WdtTh[(size_t)(d0 + ty + j) * 64 + r0 + tx] = h;
        WdtTl[(size_t)(d0 + ty + j) * 64 + r0 + tx] = f2bf(v - bf2f(h));
    }
}

// ---------------- Transpose x [2048][1024] -> xT [1024][2048] ----------------
__global__ __launch_bounds__(256) void k_transp(const float* __restrict__ in,
                                                float* __restrict__ out) {
    __shared__ float tile[32][33];
    int x0 = blockIdx.x * 32;
    int y0 = blockIdx.y * 32;
    int tx = threadIdx.x & 31, ty = threadIdx.x >> 5;
#pragma unroll
    for (int j = 0; j < 32; j += 8)
        tile[ty + j][tx] = in[(size_t)(y0 + ty + j) * 1024 + x0 + tx];
    __syncthreads();
#pragma unroll
    for (int j = 0; j < 32; j += 8)
        out[(size_t)(x0 + ty + j) * 2048 + y0 + tx] = tile[tx][ty + j];
}

// ---------------- xdbl via MFMA split, split-K: part[slice][2048][96] ----------------
// grid 256 = 64 m-blocks x 4 k-slices; block: M=32, N=96, K=256 (4 chunks of 64)
// LDS XOR-swizzle (byte ^= (row&7)<<4) keeps ds_read_b128 frag loads conflict-free.
__global__ __launch_bounds__(256) void k_xdbl3(const unsigned short* __restrict__ xh,
                                               const unsigned short* __restrict__ xl,
                                               const unsigned short* __restrict__ WxTh,
                                               const unsigned short* __restrict__ WxTl,
                                               float* __restrict__ part) {
    __shared__ unsigned short Ah[32 * 64], Al[32 * 64];
    __shared__ unsigned short Bh[96 * 64], Bl[96 * 64];
    int bm = (blockIdx.x >> 2) * 32;
    int slice = blockIdx.x & 3;
    int tid = threadIdx.x, lane = tid & 63, w = tid >> 6;
    int wm = w >> 1, wn = w & 1;
    int r = lane & 15, kb = lane >> 4;

    f32x4 acc[3];
#pragma unroll
    for (int nf = 0; nf < 3; ++nf) acc[nf] = (f32x4){0.f, 0.f, 0.f, 0.f};

#pragma unroll 1
    for (int kc = 0; kc < 4; ++kc) {
        int kbase = slice * 256 + kc * 64;
        __syncthreads();
        {   // stage A tile: 32 rows x 64 k (hi+lo); 8 lanes cover one 128B row
            int row = tid >> 3, cc = tid & 7;
            size_t src = (size_t)(bm + row) * 1024 + kbase + cc * 8;
            int dstB = row * 128 + ((cc * 16) ^ ((row & 7) << 4));
            *(s16x8*)((char*)Ah + dstB) = *(const s16x8*)&xh[src];
            *(s16x8*)((char*)Al + dstB) = *(const s16x8*)&xl[src];
        }
#pragma unroll
        for (int j = 0; j < 3; ++j) {  // stage B tile: 96 rows x 64 k
            int c = tid + j * 256;
            int row = c >> 3, cc = c & 7;
            size_t src = (size_t)row * 1024 + kbase + cc * 8;
            int dstB = row * 128 + ((cc * 16) ^ ((row & 7) << 4));
            *(s16x8*)((char*)Bh + dstB) = *(const s16x8*)&WxTh[src];
            *(s16x8*)((char*)Bl + dstB) = *(const s16x8*)&WxTl[src];
        }
        __syncthreads();
#pragma unroll
        for (int ks = 0; ks < 2; ++ks) {
            int sw = (ks * 64 + kb * 16) ^ ((r & 7) << 4);
            s16x8 a_h = *(const s16x8*)((char*)Ah + (wm * 16 + r) * 128 + sw);
            s16x8 a_l = *(const s16x8*)((char*)Al + (wm * 16 + r) * 128 + sw);
#pragma unroll
            for (int nf = 0; nf < 3; ++nf) {
                int brow = wn * 48 + nf * 16 + r;
                s16x8 b_h = *(const s16x8*)((char*)Bh + brow * 128 + sw);
                s16x8 b_l = *(const s16x8*)((char*)Bl + brow * 128 + sw);
                acc[nf] = __builtin_amdgcn_mfma_f32_16x16x32_bf16(a_h, b_h, acc[nf], 0, 0, 0);
                acc[nf] = __builtin_amdgcn_mfma_f32_16x16x32_bf16(a_h, b_l, acc[nf], 0, 0, 0);
                acc[nf] = __builtin_amdgcn_mfma_f32_16x16x32_bf16(a_l, b_h, acc[nf], 0, 0, 0);
            }
        }
    }
    float* pb = part + (size_t)slice * 2048 * 96;
#pragma unroll
    for (int nf = 0; nf < 3; ++nf)
#pragma unroll
        for (int j = 0; j < 4; ++j)
            pb[(size_t)(bm + wm * 16 + kb * 4 + j) * 96 + wn * 48 + nf * 16 + r] = acc[nf][j];
}

// ---------------- reduce 4 k-slices -> xdh/xdl (delta cols) + bpk/cpk ----------------
__global__ __launch_bounds__(256) void k_xred(const float* __restrict__ part,
                                              unsigned short* __restrict__ xdh,
                                              unsigned short* __restrict__ xdl,
                                              float* __restrict__ bpk,
                                              float* __restrict__ cpk) {
    int gid = blockIdx.x * 256 + threadIdx.x;
    int f = gid * 4;
    int m = f / 96;
    int col = f - m * 96;
    f32x4 v = *(const f32x4*)&part[f];
#pragma unroll
    for (int s = 1; s < 4; ++s)
        v += *(const f32x4*)&part[(size_t)s * 2048 * 96 + f];
    if (col < 64) {
        ushort4 h, l;
        float e0 = v[0], e1 = v[1], e2 = v[2], e3 = v[3];
        h.x = f2bf(e0); l.x = f2bf(e0 - bf2f(h.x));
        h.y = f2bf(e1); l.y = f2bf(e1 - bf2f(h.y));
        h.z = f2bf(e2); l.z = f2bf(e2 - bf2f(h.z));
        h.w = f2bf(e3); l.w = f2bf(e3 - bf2f(h.w));
        *(ushort4*)&xdh[(size_t)m * 64 + col] = h;
        *(ushort4*)&xdl[(size_t)m * 64 + col] = l;
    } else if (col < 80) {
        *(f32x4*)&bpk[(size_t)m * 16 + col - 64] = v;
    } else {
        *(f32x4*)&cpk[(size_t)m * 16 + col - 80] = v;
    }
}

// ---------------- delta via MFMA split: M=2048 N=1024 K=64 -> softplus -> deltaT [d][m] ----------------
__global__ __launch_bounds__(256) void k_delta2(const unsigned short* __restrict__ xdh,
                                                const unsigned short* __restrict__ xdl,
                                                const unsigned short* __restrict__ WdtTh,
                                                const unsigned short* __restrict__ WdtTl,
                                                const float* __restrict__ bdt,
                                                float* __restrict__ deltaT) {
    __shared__ float slab[4][32][68];
    int bm = blockIdx.y * 128;
    int bn = blockIdx.x * 128;
    int tid = threadIdx.x, lane = tid & 63, w = tid >> 6;
    int wm = w >> 1, wn = w & 1;
    int r = lane & 15, kb = lane >> 4;

    f32x4 acc[4][4];
#pragma unroll
    for (int mf = 0; mf < 4; ++mf)
#pragma unroll
        for (int nf = 0; nf < 4; ++nf) acc[mf][nf] = (f32x4){0.f, 0.f, 0.f, 0.f};

#pragma unroll
    for (int ks = 0; ks < 2; ++ks) {
        s16x8 Ah[4], Al[4], Bh[4], Bl[4];
#pragma unroll
        for (int mf = 0; mf < 4; ++mf) {
            size_t a = (size_t)(bm + wm * 64 + mf * 16 + r) * 64 + ks * 32 + kb * 8;
            Ah[mf] = *(const s16x8*)&xdh[a];
            Al[mf] = *(const s16x8*)&xdl[a];
        }
#pragma unroll
        for (int nf = 0; nf < 4; ++nf) {
            size_t b = (size_t)(bn + wn * 64 + nf * 16 + r) * 64 + ks * 32 + kb * 8;
            Bh[nf] = *(const s16x8*)&WdtTh[b];
            Bl[nf] = *(const s16x8*)&WdtTl[b];
        }
#pragma unroll
        for (int mf = 0; mf < 4; ++mf)
#pragma unroll
            for (int nf = 0; nf < 4; ++nf) {
                acc[mf][nf] = __builtin_amdgcn_mfma_f32_16x16x32_bf16(Ah[mf], Bh[nf], acc[mf][nf], 0, 0, 0);
                acc[mf][nf] = __builtin_amdgcn_mfma_f32_16x16x32_bf16(Ah[mf], Bl[nf], acc[mf][nf], 0, 0, 0);
                acc[mf][nf] = __builtin_amdgcn_mfma_f32_16x16x32_bf16(Al[mf], Bh[nf], acc[mf][nf], 0, 0, 0);
            }
    }

#pragma unroll
    for (int half = 0; half < 2; ++half) {
#pragma unroll
        for (int nf2 = 0; nf2 < 2; ++nf2) {
            int nf = half * 2 + nf2;
            float bb = bdt[bn + wn * 64 + nf * 16 + r];
#pragma unroll
            for (int mf = 0; mf < 4; ++mf)
#pragma unroll
                for (int j = 0; j < 4; ++j) {
                    float z = acc[mf][nf][j] + bb;
                    float sp = fmaxf(z, 0.f) + log1pf(expf(-fabsf(z)));
                    slab[w][nf2 * 16 + r][mf * 16 + kb * 4 + j] = sp;
                }
        }
#pragma unroll
        for (int i = 0; i < 8; ++i) {
            int idx = i * 64 + lane;
            int dl = idx >> 4, mq = (idx & 15) * 4;
            f32x4 v = *(const f32x4*)&slab[w][dl][mq];
            *(f32x4*)&deltaT[(size_t)(bn + wn * 64 + half * 32 + dl) * MTOT + bm + wm * 64 + mq] = v;
        }
    }
}

// ---------------- Kernel C: chunked selective scan -> yT bf16 [d][m] ----------------
__global__ __launch_bounds__(256) void k_scan3(const float* __restrict__ deltaT,
                                               const float* __restrict__ xT,
                                               const float* __restrict__ bpk,
                                               const float* __restrict__ cpk,
                                               const float* __restrict__ Alog,
                                               const float* __restrict__ Dp,
                                               unsigned short* __restrict__ yTbf) {
    __shared__ double csum[64];
    __shared__ double Rbef[64];
    __shared__ float TcL[64 * 20];
    __shared__ float syp[64 * 17];

    int tid = threadIdx.x;
    int c = tid >> 2, l = tid & 3;
    int w = tid >> 6, lane = tid & 63;
    int d = blockIdx.x & 1023, b = blockIdx.x >> 10;
    int m0 = b * 1024;

    const f32x4* dp = (const f32x4*)(deltaT + (size_t)d * MTOT + m0 + c * 16);
    const f32x4* up = (const f32x4*)(xT + (size_t)d * MTOT + m0 + c * 16);
    const f32x4* Bp = (const f32x4*)bpk + (size_t)(m0 + c * 16) * 4 + l;
    const f32x4* Cp = (const f32x4*)cpk + (size_t)(m0 + c * 16) * 4 + l;

    double dsum = 0.0;
#pragma unroll
    for (int i = 0; i < 4; ++i) {
        f32x4 v = dp[i];
        dsum += (double)v[0] + (double)v[1] + (double)v[2] + (double)v[3];
    }
    if (l == 0) csum[c] = dsum;
    __syncthreads();
    if (tid < 64) {
        double v = csum[tid];
#pragma unroll
        for (int off = 1; off < 64; off <<= 1) {
            double t = __shfl_down(v, off, 64);
            if (tid + off < 64) v += t;
        }
        Rbef[tid] = v;
    }
    __syncthreads();

    float Af[4], Sb[4];
    double Rb = Rbef[c];
#pragma unroll
    for (int j = 0; j < 4; ++j) {
        Af[j] = -__expf(Alog[d * NSTATE + 4 * l + j]);
        Sb[j] = (float)((double)Af[j] * Rb);
    }
    float Dv = Dp[d];

    float P = 0.f;
    f32x4 Tn = {0.f, 0.f, 0.f, 0.f};
#pragma unroll 1
    for (int t4 = 0; t4 < 4; ++t4) {
        f32x4 rdv = dp[t4];
        f32x4 ruv = up[t4];
        f32x4 Bq0 = Bp[(t4 * 4 + 0) * 4];
        f32x4 Bq1 = Bp[(t4 * 4 + 1) * 4];
        f32x4 Bq2 = Bp[(t4 * 4 + 2) * 4];
        f32x4 Bq3 = Bp[(t4 * 4 + 3) * 4];
        f32x4 Bq[4] = {Bq0, Bq1, Bq2, Bq3};
#pragma unroll
        for (int k = 0; k < 4; ++k) {
            float dlt = rdv[k];
            P += dlt;
            float du = dlt * ruv[k];
#pragma unroll
            for (int j = 0; j < 4; ++j) {
                float e = __expf(fmaf(-Af[j], P, Sb[j]));
                Tn[j] = fmaf(du * Bq[k][j], e, Tn[j]);
            }
        }
    }
    *(f32x4*)&TcL[c * 20 + 4 * l] = Tn;
    __syncthreads();

    {
        f32x4 v = *(const f32x4*)&TcL[lane * 20 + 4 * w];
#pragma unroll
        for (int off = 1; off < 64; off <<= 1) {
            f32x4 t = shflup4(v, off);
            if (lane >= off) v += t;
        }
        f32x4 ex = shflup4(v, 1);
        if (lane == 0) ex = (f32x4){0.f, 0.f, 0.f, 0.f};
        *(f32x4*)&TcL[lane * 20 + 4 * w] = ex;
    }
    __syncthreads();
    f32x4 num = *(const f32x4*)&TcL[c * 20 + 4 * l];

    P = 0.f;
#pragma unroll 1
    for (int t4 = 0; t4 < 4; ++t4) {
        f32x4 rdv = dp[t4];
        f32x4 ruv = up[t4];
        f32x4 Bq[4], Cq[4];
#pragma unroll
        for (int k = 0; k < 4; ++k) {
            Bq[k] = Bp[(t4 * 4 + k) * 4];
            Cq[k] = Cp[(t4 * 4 + k) * 4];
        }
#pragma unroll
        for (int k = 0; k < 4; ++k) {
            float dlt = rdv[k];
            P += dlt;
            float du = dlt * ruv[k];
            float psum = 0.f;
#pragma unroll
            for (int j = 0; j < 4; ++j) {
                float e = __expf(fmaf(-Af[j], P, Sb[j]));
                num[j] = fmaf(du * Bq[k][j], e, num[j]);
                float rr = __builtin_amdgcn_rcpf(e + 1e-12f);
                psum = fmaf(num[j] * rr, Cq[k][j], psum);
            }
            psum += __shfl_xor(psum, 1);
            psum += __shfl_xor(psum, 2);
            if (l == 0) syp[c * 17 + t4 * 4 + k] = fmaf(ruv[k], Dv, psum);
        }
    }
    __syncthreads();
    {
        int cc = tid >> 2, oo = (tid & 3) * 4;
        const float* sp = &syp[cc * 17 + oo];
        ushort4 o;
        o.x = f2bf(sp[0]);
        o.y = f2bf(sp[1]);
        o.z = f2bf(sp[2]);
        o.w = f2bf(sp[3]);
        *reinterpret_cast<ushort4*>(&yTbf[(size_t)d * MTOT + m0 + tid * 4]) = o;
    }
}

// ---------------- W_out [k][e] f32 -> WbfT [e][k] bf16 ----------------
__global__ __launch_bounds__(256) void k_wconv(const float* __restrict__ W,
                                               unsigned short* __restrict__ WT) {
    __shared__ float t[64][65];
    int k0 = blockIdx.y * 64, e0 = blockIdx.x * 64;
    int tx = threadIdx.x & 63, ty = threadIdx.x >> 6;
#pragma unroll
    for (int j = 0; j < 64; j += 4)
        t[ty + j][tx] = W[(size_t)(k0 + ty + j) * 1024 + e0 + tx];
    __syncthreads();
#pragma unroll
    for (int j = 0; j < 64; j += 4)
        WT[(size_t)(e0 + ty + j) * 1024 + k0 + tx] = f2bf(t[tx][ty + j]);
}

// ---------------- yTbf [d][m] bf16 -> ybf [m][d] bf16 ----------------
__global__ __launch_bounds__(256) void k_ytr(const unsigned short* __restrict__ in,
                                             unsigned short* __restrict__ out) {
    __shared__ unsigned short t[64][66];
    int d0 = blockIdx.y * 64, m0 = blockIdx.x * 64;
    int tx = threadIdx.x & 63, ty = threadIdx.x >> 6;
#pragma unroll
    for (int j = 0; j < 64; j += 4)
        t[ty + j][tx] = in[(size_t)(d0 + ty + j) * MTOT + m0 + tx];
    __syncthreads();
#pragma unroll
    for (int j = 0; j < 64; j += 4)
        out[(size_t)(m0 + ty + j) * 1024 + d0 + tx] = t[tx][ty + j];
}

// ---------------- Kernel D: out = ybf @ WbfT^T + b_out via MFMA ----------------
__global__ __launch_bounds__(256) void k_gemm(const unsigned short* __restrict__ A,
                                              const unsigned short* __restrict__ B,
                                              const float* __restrict__ bias,
                                              float* __restrict__ out) {
    __shared__ unsigned short As[128 * 64];
    __shared__ unsigned short Bs[64 * 64];
    const int GN = 1024, GK = 1024;
    int bm = blockIdx.y * 128;
    int bn = blockIdx.x * 64;
    int tid = threadIdx.x;
    int lane = tid & 63;
    int w = tid >> 6;
    int wm = w >> 1, wn = w & 1;
    int r = lane & 15, kb = lane >> 4;

    f32x4 zero4 = {0.f, 0.f, 0.f, 0.f};
    f32x4 acc[4][2];
#pragma unroll
    for (int mf = 0; mf < 4; ++mf)
#pragma unroll
        for (int nf = 0; nf < 2; ++nf) acc[mf][nf] = zero4;

    s16x8 ra[4], rb[2];
    auto stage_load = [&](int k0) {
#pragma unroll
        for (int i = 0; i < 4; ++i) {
            int q = tid + i * 256;
            ra[i] = *reinterpret_cast<const s16x8*>(&A[(size_t)(bm + (q >> 3)) * GK + k0 + (q & 7) * 8]);
        }
#pragma unroll
        for (int i = 0; i < 2; ++i) {
            int q = tid + i * 256;
            rb[i] = *reinterpret_cast<const s16x8*>(&B[(size_t)(bn + (q >> 3)) * GK + k0 + (q & 7) * 8]);
        }
    };

    stage_load(0);
    for (int k0 = 0; k0 < GK; k0 += 64) {
        __syncthreads();
#pragma unroll
        for (int i = 0; i < 4; ++i)
            *reinterpret_cast<s16x8*>(&As[(tid + i * 256) * 8]) = ra[i];
#pragma unroll
        for (int i = 0; i < 2; ++i)
            *reinterpret_cast<s16x8*>(&Bs[(tid + i * 256) * 8]) = rb[i];
        __syncthreads();
        if (k0 + 64 < GK) stage_load(k0 + 64);
#pragma unroll
        for (int ks = 0; ks < 2; ++ks) {
            s16x8 af[4], bfr[2];
#pragma unroll
            for (int mf = 0; mf < 4; ++mf)
                af[mf] = *reinterpret_cast<const s16x8*>(&As[(wm * 64 + mf * 16 + r) * 64 + ks * 32 + kb * 8]);
#pragma unroll
            for (int nf = 0; nf < 2; ++nf)
                bfr[nf] = *reinterpret_cast<const s16x8*>(&Bs[(wn * 32 + nf * 16 + r) * 64 + ks * 32 + kb * 8]);
#pragma unroll
            for (int mf = 0; mf < 4; ++mf)
#pragma unroll
                for (int nf = 0; nf < 2; ++nf)
                    acc[mf][nf] = __builtin_amdgcn_mfma_f32_16x16x32_bf16(af[mf], bfr[nf], acc[mf][nf], 0, 0, 0);
        }
    }
#pragma unroll
    for (int nf = 0; nf < 2; ++nf) {
        float bb = bias[bn + wn * 32 + nf * 16 + r];
#pragma unroll
        for (int mf = 0; mf < 4; ++mf)
#pragma unroll
            for (int j = 0; j < 4; ++j)
                out[(size_t)(bm + wm * 64 + mf * 16 + kb * 4 + j) * GN + bn + wn * 32 + nf * 16 + r] =
                    acc[mf][nf][j] + bb;
    }
}

extern "C" void kernel_launch(void* const* d_in, const int* in_sizes, int n_in,
                              void* d_out, int out_size, void* d_ws, size_t ws_size,
                              hipStream_t stream) {
    const float* x    = (const float*)d_in[0];
    const float* Wx   = (const float*)d_in[1];
    const float* Wdt  = (const float*)d_in[2];
    const float* bdt  = (const float*)d_in[3];
    const float* Alog = (const float*)d_in[4];
    const float* Dp   = (const float*)d_in[5];
    const float* Wout = (const float*)d_in[6];
    const float* bout = (const float*)d_in[7];
    float* out = (float*)d_out;

    float* xT     = (float*)d_ws;                          // 1024*2048 f
    float* deltaT = xT + 1024 * 2048;                      // 1024*2048 f
    float* bpk    = deltaT + 1024 * 2048;                  // 2048*16 f
    float* cpk    = bpk + 2048 * 16;                       // 2048*16 f
    float* part   = cpk + 2048 * 16;                       // 4*2048*96 f
    unsigned short* xh    = (unsigned short*)(part + 4 * 2048 * 96);
    unsigned short* xl    = xh + 2048 * 1024;
    unsigned short* WxTh  = xl + 2048 * 1024;              // 96*1024
    unsigned short* WxTl  = WxTh + 96 * 1024;
    unsigned short* WdtTh = WxTl + 96 * 1024;              // 1024*64
    unsigned short* WdtTl = WdtTh + 1024 * 64;
    unsigned short* xdh   = WdtTl + 1024 * 64;             // 2048*64
    unsigned short* xdl   = xdh + 2048 * 64;
    unsigned short* yTbf  = xdl + 2048 * 64;               // 1024*2048
    unsigned short* ybf   = yTbf + 1024 * 2048;            // 2048*1024
    unsigned short* WbfT  = ybf + 2048 * 1024;             // 1024*1024

    k_splitx<<<1024, 256, 0, stream>>>(x, xh, xl);
    k_wxT<<<dim3(3, 32), 256, 0, stream>>>(Wx, WxTh, WxTl);
    k_wdtT<<<dim3(32, 2), 256, 0, stream>>>(Wdt, WdtTh, WdtTl);
    k_wconv<<<dim3(16, 16), 256, 0, stream>>>(Wout, WbfT);
    k_transp<<<dim3(32, 64), 256, 0, stream>>>(x, xT);
    k_xdbl3<<<256, 256, 0, stream>>>(xh, xl, WxTh, WxTl, part);
    k_xred<<<192, 256, 0, stream>>>(part, xdh, xdl, bpk, cpk);
    k_delta2<<<dim3(8, 16), 256, 0, stream>>>(xdh, xdl, WdtTh, WdtTl, bdt, deltaT);
    k_scan3<<<2048, 256, 0, stream>>>(deltaT, xT, bpk, cpk, Alog, Dp, yTbf);
    k_ytr<<<dim3(32, 16), 256, 0, stream>>>(yTbf, ybf);
    k_gemm<<<dim3(16, 16), 256, 0, stream>>>(ybf, WbfT, bout, out);
}

// Round 7
// 81.070 us; speedup vs baseline: 1.8640x; 1.1370x over previous
//
#include <hip/hip_runtime.h>
#include <hip/hip_bf16.h>

// b=2, L=1024, d=1024, dt_rank=64, n=16, E=96
#define LSEQ 1024
#define DMODEL 1024
#define NSTATE 16
#define DTRANK 64
#define ECOL 96
#define MTOT 2048

typedef short s16x8 __attribute__((ext_vector_type(8)));
typedef float f32x4 __attribute__((ext_vector_type(4)));

__device__ inline unsigned short f2bf(float f) {
    unsigned int u = __builtin_bit_cast(unsigned int, f);
    u += 0x7FFFu + ((u >> 16) & 1u);
    return (unsigned short)(u >> 16);
}
__device__ inline float bf2f(unsigned short h) {
    unsigned int u = ((unsigned int)h) << 16;
    return __builtin_bit_cast(float, u);
}

__device__ inline f32x4 shflup4(f32x4 v, int off) {
    f32x4 r;
    r[0] = __shfl_up(v[0], off, 64);
    r[1] = __shfl_up(v[1], off, 64);
    r[2] = __shfl_up(v[2], off, 64);
    r[3] = __shfl_up(v[3], off, 64);
    return r;
}

// ---------------- fused prep: x->{xT,xh,xl}, Wx->WxT h/l, Wdt->WdtT h/l, Wout->WbfT ----------------
// grid: [0,512) x-tiles 64x64 | [512,608) WxT | [608,672) WdtT | [672,928) WbfT
__global__ __launch_bounds__(256) void k_prep(const float* __restrict__ x,
                                              const float* __restrict__ Wx,
                                              const float* __restrict__ Wdt,
                                              const float* __restrict__ Wout,
                                              float* __restrict__ xT,
                                              unsigned short* __restrict__ xh,
                                              unsigned short* __restrict__ xl,
                                              unsigned short* __restrict__ WxTh,
                                              unsigned short* __restrict__ WxTl,
                                              unsigned short* __restrict__ WdtTh,
                                              unsigned short* __restrict__ WdtTl,
                                              unsigned short* __restrict__ WbfT) {
    __shared__ float t[64][65];
    int id = blockIdx.x;
    int tid = threadIdx.x;
    if (id < 512) {
        int d0 = (id & 15) * 64, m0 = (id >> 4) * 64;
        int tx = tid & 63, ty = tid >> 6;
#pragma unroll
        for (int j = 0; j < 64; j += 4) {
            size_t src = (size_t)(m0 + ty + j) * 1024 + d0 + tx;
            float v = x[src];
            t[ty + j][tx] = v;
            unsigned short h = f2bf(v);
            xh[src] = h;
            xl[src] = f2bf(v - bf2f(h));
        }
        __syncthreads();
#pragma unroll
        for (int j = 0; j < 64; j += 4)
            xT[(size_t)(d0 + ty + j) * 2048 + m0 + tx] = t[tx][ty + j];
    } else if (id < 512 + 96) {
        int id2 = id - 512;
        int e0 = (id2 % 3) * 32, k0 = (id2 / 3) * 32;
        int tx = tid & 31, ty = tid >> 5;  // ty 0..7
#pragma unroll
        for (int j = 0; j < 32; j += 8)
            t[ty + j][tx] = Wx[(size_t)(k0 + ty + j) * 96 + e0 + tx];
        __syncthreads();
#pragma unroll
        for (int j = 0; j < 32; j += 8) {
            float v = t[tx][ty + j];
            unsigned short h = f2bf(v);
            WxTh[(size_t)(e0 + ty + j) * 1024 + k0 + tx] = h;
            WxTl[(size_t)(e0 + ty + j) * 1024 + k0 + tx] = f2bf(v - bf2f(h));
        }
    } else if (id < 512 + 96 + 64) {
        int id3 = id - (512 + 96);
        int d0 = (id3 & 31) * 32, r0 = (id3 >> 5) * 32;
        int tx = tid & 31, ty = tid >> 5;
#pragma unroll
        for (int j = 0; j < 32; j += 8)
            t[ty + j][tx] = Wdt[(size_t)(r0 + ty + j) * 1024 + d0 + tx];
        __syncthreads();
#pragma unroll
        for (int j = 0; j < 32; j += 8) {
            float v = t[tx][ty + j];
            unsigned short h = f2bf(v);
            WdtTh[(size_t)(d0 + ty + j) * 64 + r0 + tx] = h;
            WdtTl[(size_t)(d0 + ty + j) * 64 + r0 + tx] = f2bf(v - bf2f(h));
        }
    } else {
        int id4 = id - (512 + 96 + 64);
        int e0 = (id4 & 15) * 64, k0 = (id4 >> 4) * 64;
        int tx = tid & 63, ty = tid >> 6;
#pragma unroll
        for (int j = 0; j < 64; j += 4)
            t[ty + j][tx] = Wout[(size_t)(k0 + ty + j) * 1024 + e0 + tx];
        __syncthreads();
#pragma unroll
        for (int j = 0; j < 64; j += 4)
            WbfT[(size_t)(e0 + ty + j) * 1024 + k0 + tx] = f2bf(t[tx][ty + j]);
    }
}

// ---------------- xdbl via MFMA split, split-K: part[slice][2048][96] ----------------
__global__ __launch_bounds__(256) void k_xdbl3(const unsigned short* __restrict__ xh,
                                               const unsigned short* __restrict__ xl,
                                               const unsigned short* __restrict__ WxTh,
                                               const unsigned short* __restrict__ WxTl,
                                               float* __restrict__ part) {
    __shared__ unsigned short Ah[32 * 64], Al[32 * 64];
    __shared__ unsigned short Bh[96 * 64], Bl[96 * 64];
    int bm = (blockIdx.x >> 2) * 32;
    int slice = blockIdx.x & 3;
    int tid = threadIdx.x, lane = tid & 63, w = tid >> 6;
    int wm = w >> 1, wn = w & 1;
    int r = lane & 15, kb = lane >> 4;

    f32x4 acc[3];
#pragma unroll
    for (int nf = 0; nf < 3; ++nf) acc[nf] = (f32x4){0.f, 0.f, 0.f, 0.f};

#pragma unroll 1
    for (int kc = 0; kc < 4; ++kc) {
        int kbase = slice * 256 + kc * 64;
        __syncthreads();
        {
            int row = tid >> 3, cc = tid & 7;
            size_t src = (size_t)(bm + row) * 1024 + kbase + cc * 8;
            int dstB = row * 128 + ((cc * 16) ^ ((row & 7) << 4));
            *(s16x8*)((char*)Ah + dstB) = *(const s16x8*)&xh[src];
            *(s16x8*)((char*)Al + dstB) = *(const s16x8*)&xl[src];
        }
#pragma unroll
        for (int j = 0; j < 3; ++j) {
            int c = tid + j * 256;
            int row = c >> 3, cc = c & 7;
            size_t src = (size_t)row * 1024 + kbase + cc * 8;
            int dstB = row * 128 + ((cc * 16) ^ ((row & 7) << 4));
            *(s16x8*)((char*)Bh + dstB) = *(const s16x8*)&WxTh[src];
            *(s16x8*)((char*)Bl + dstB) = *(const s16x8*)&WxTl[src];
        }
        __syncthreads();
#pragma unroll
        for (int ks = 0; ks < 2; ++ks) {
            int sw = (ks * 64 + kb * 16) ^ ((r & 7) << 4);
            s16x8 a_h = *(const s16x8*)((char*)Ah + (wm * 16 + r) * 128 + sw);
            s16x8 a_l = *(const s16x8*)((char*)Al + (wm * 16 + r) * 128 + sw);
#pragma unroll
            for (int nf = 0; nf < 3; ++nf) {
                int brow = wn * 48 + nf * 16 + r;
                s16x8 b_h = *(const s16x8*)((char*)Bh + brow * 128 + sw);
                s16x8 b_l = *(const s16x8*)((char*)Bl + brow * 128 + sw);
                acc[nf] = __builtin_amdgcn_mfma_f32_16x16x32_bf16(a_h, b_h, acc[nf], 0, 0, 0);
                acc[nf] = __builtin_amdgcn_mfma_f32_16x16x32_bf16(a_h, b_l, acc[nf], 0, 0, 0);
                acc[nf] = __builtin_amdgcn_mfma_f32_16x16x32_bf16(a_l, b_h, acc[nf], 0, 0, 0);
            }
        }
    }
    float* pb = part + (size_t)slice * 2048 * 96;
#pragma unroll
    for (int nf = 0; nf < 3; ++nf)
#pragma unroll
        for (int j = 0; j < 4; ++j)
            pb[(size_t)(bm + wm * 16 + kb * 4 + j) * 96 + wn * 48 + nf * 16 + r] = acc[nf][j];
}

// ---------------- reduce 4 k-slices -> xdh/xdl + bpk/cpk ----------------
__global__ __launch_bounds__(256) void k_xred(const float* __restrict__ part,
                                              unsigned short* __restrict__ xdh,
                                              unsigned short* __restrict__ xdl,
                                              float* __restrict__ bpk,
                                              float* __restrict__ cpk) {
    int gid = blockIdx.x * 256 + threadIdx.x;
    int f = gid * 4;
    int m = f / 96;
    int col = f - m * 96;
    f32x4 v = *(const f32x4*)&part[f];
#pragma unroll
    for (int s = 1; s < 4; ++s)
        v += *(const f32x4*)&part[(size_t)s * 2048 * 96 + f];
    if (col < 64) {
        ushort4 h, l;
        float e0 = v[0], e1 = v[1], e2 = v[2], e3 = v[3];
        h.x = f2bf(e0); l.x = f2bf(e0 - bf2f(h.x));
        h.y = f2bf(e1); l.y = f2bf(e1 - bf2f(h.y));
        h.z = f2bf(e2); l.z = f2bf(e2 - bf2f(h.z));
        h.w = f2bf(e3); l.w = f2bf(e3 - bf2f(h.w));
        *(ushort4*)&xdh[(size_t)m * 64 + col] = h;
        *(ushort4*)&xdl[(size_t)m * 64 + col] = l;
    } else if (col < 80) {
        *(f32x4*)&bpk[(size_t)m * 16 + col - 64] = v;
    } else {
        *(f32x4*)&cpk[(size_t)m * 16 + col - 80] = v;
    }
}

// ---------------- delta via MFMA split: M=2048 N=1024 K=64 -> softplus -> deltaT [d][m] ----------------
__global__ __launch_bounds__(256) void k_delta2(const unsigned short* __restrict__ xdh,
                                                const unsigned short* __restrict__ xdl,
                                                const unsigned short* __restrict__ WdtTh,
                                                const unsigned short* __restrict__ WdtTl,
                                                const float* __restrict__ bdt,
                                                float* __restrict__ deltaT) {
    __shared__ float slab[4][32][68];
    int bm = blockIdx.y * 128;
    int bn = blockIdx.x * 128;
    int tid = threadIdx.x, lane = tid & 63, w = tid >> 6;
    int wm = w >> 1, wn = w & 1;
    int r = lane & 15, kb = lane >> 4;

    f32x4 acc[4][4];
#pragma unroll
    for (int mf = 0; mf < 4; ++mf)
#pragma unroll
        for (int nf = 0; nf < 4; ++nf) acc[mf][nf] = (f32x4){0.f, 0.f, 0.f, 0.f};

#pragma unroll
    for (int ks = 0; ks < 2; ++ks) {
        s16x8 Ah[4], Al[4], Bh[4], Bl[4];
#pragma unroll
        for (int mf = 0; mf < 4; ++mf) {
            size_t a = (size_t)(bm + wm * 64 + mf * 16 + r) * 64 + ks * 32 + kb * 8;
            Ah[mf] = *(const s16x8*)&xdh[a];
            Al[mf] = *(const s16x8*)&xdl[a];
        }
#pragma unroll
        for (int nf = 0; nf < 4; ++nf) {
            size_t b = (size_t)(bn + wn * 64 + nf * 16 + r) * 64 + ks * 32 + kb * 8;
            Bh[nf] = *(const s16x8*)&WdtTh[b];
            Bl[nf] = *(const s16x8*)&WdtTl[b];
        }
#pragma unroll
        for (int mf = 0; mf < 4; ++mf)
#pragma unroll
            for (int nf = 0; nf < 4; ++nf) {
                acc[mf][nf] = __builtin_amdgcn_mfma_f32_16x16x32_bf16(Ah[mf], Bh[nf], acc[mf][nf], 0, 0, 0);
                acc[mf][nf] = __builtin_amdgcn_mfma_f32_16x16x32_bf16(Ah[mf], Bl[nf], acc[mf][nf], 0, 0, 0);
                acc[mf][nf] = __builtin_amdgcn_mfma_f32_16x16x32_bf16(Al[mf], Bh[nf], acc[mf][nf], 0, 0, 0);
            }
    }

#pragma unroll
    for (int half = 0; half < 2; ++half) {
#pragma unroll
        for (int nf2 = 0; nf2 < 2; ++nf2) {
            int nf = half * 2 + nf2;
            float bb = bdt[bn + wn * 64 + nf * 16 + r];
#pragma unroll
            for (int mf = 0; mf < 4; ++mf)
#pragma unroll
                for (int j = 0; j < 4; ++j) {
                    float z = acc[mf][nf][j] + bb;
                    float sp = fmaxf(z, 0.f) + log1pf(expf(-fabsf(z)));
                    slab[w][nf2 * 16 + r][mf * 16 + kb * 4 + j] = sp;
                }
        }
#pragma unroll
        for (int i = 0; i < 8; ++i) {
            int idx = i * 64 + lane;
            int dl = idx >> 4, mq = (idx & 15) * 4;
            f32x4 v = *(const f32x4*)&slab[w][dl][mq];
            *(f32x4*)&deltaT[(size_t)(bn + wn * 64 + half * 32 + dl) * MTOT + bm + wm * 64 + mq] = v;
        }
    }
}

// ---------------- Kernel C: chunked selective scan -> yT bf16 [d][m] ----------------
__global__ __launch_bounds__(256) void k_scan3(const float* __restrict__ deltaT,
                                               const float* __restrict__ xT,
                                               const float* __restrict__ bpk,
                                               const float* __restrict__ cpk,
                                               const float* __restrict__ Alog,
                                               const float* __restrict__ Dp,
                                               unsigned short* __restrict__ yTbf) {
    __shared__ double csum[64];
    __shared__ double Rbef[64];
    __shared__ float TcL[64 * 20];
    __shared__ float syp[64 * 17];

    int tid = threadIdx.x;
    int c = tid >> 2, l = tid & 3;
    int w = tid >> 6, lane = tid & 63;
    int d = blockIdx.x & 1023, b = blockIdx.x >> 10;
    int m0 = b * 1024;

    const f32x4* dp = (const f32x4*)(deltaT + (size_t)d * MTOT + m0 + c * 16);
    const f32x4* up = (const f32x4*)(xT + (size_t)d * MTOT + m0 + c * 16);
    const f32x4* Bp = (const f32x4*)bpk + (size_t)(m0 + c * 16) * 4 + l;
    const f32x4* Cp = (const f32x4*)cpk + (size_t)(m0 + c * 16) * 4 + l;

    double dsum = 0.0;
#pragma unroll
    for (int i = 0; i < 4; ++i) {
        f32x4 v = dp[i];
        dsum += (double)v[0] + (double)v[1] + (double)v[2] + (double)v[3];
    }
    if (l == 0) csum[c] = dsum;
    __syncthreads();
    if (tid < 64) {
        double v = csum[tid];
#pragma unroll
        for (int off = 1; off < 64; off <<= 1) {
            double t = __shfl_down(v, off, 64);
            if (tid + off < 64) v += t;
        }
        Rbef[tid] = v;
    }
    __syncthreads();

    float Af[4], Sb[4];
    double Rb = Rbef[c];
#pragma unroll
    for (int j = 0; j < 4; ++j) {
        Af[j] = -__expf(Alog[d * NSTATE + 4 * l + j]);
        Sb[j] = (float)((double)Af[j] * Rb);
    }
    float Dv = Dp[d];

    float P = 0.f;
    f32x4 Tn = {0.f, 0.f, 0.f, 0.f};
#pragma unroll 1
    for (int t4 = 0; t4 < 4; ++t4) {
        f32x4 rdv = dp[t4];
        f32x4 ruv = up[t4];
        f32x4 Bq0 = Bp[(t4 * 4 + 0) * 4];
        f32x4 Bq1 = Bp[(t4 * 4 + 1) * 4];
        f32x4 Bq2 = Bp[(t4 * 4 + 2) * 4];
        f32x4 Bq3 = Bp[(t4 * 4 + 3) * 4];
        f32x4 Bq[4] = {Bq0, Bq1, Bq2, Bq3};
#pragma unroll
        for (int k = 0; k < 4; ++k) {
            float dlt = rdv[k];
            P += dlt;
            float du = dlt * ruv[k];
#pragma unroll
            for (int j = 0; j < 4; ++j) {
                float e = __expf(fmaf(-Af[j], P, Sb[j]));
                Tn[j] = fmaf(du * Bq[k][j], e, Tn[j]);
            }
        }
    }
    *(f32x4*)&TcL[c * 20 + 4 * l] = Tn;
    __syncthreads();

    {
        f32x4 v = *(const f32x4*)&TcL[lane * 20 + 4 * w];
#pragma unroll
        for (int off = 1; off < 64; off <<= 1) {
            f32x4 t = shflup4(v, off);
            if (lane >= off) v += t;
        }
        f32x4 ex = shflup4(v, 1);
        if (lane == 0) ex = (f32x4){0.f, 0.f, 0.f, 0.f};
        *(f32x4*)&TcL[lane * 20 + 4 * w] = ex;
    }
    __syncthreads();
    f32x4 num = *(const f32x4*)&TcL[c * 20 + 4 * l];

    P = 0.f;
#pragma unroll 1
    for (int t4 = 0; t4 < 4; ++t4) {
        f32x4 rdv = dp[t4];
        f32x4 ruv = up[t4];
        f32x4 Bq[4], Cq[4];
#pragma unroll
        for (int k = 0; k < 4; ++k) {
            Bq[k] = Bp[(t4 * 4 + k) * 4];
            Cq[k] = Cp[(t4 * 4 + k) * 4];
        }
#pragma unroll
        for (int k = 0; k < 4; ++k) {
            float dlt = rdv[k];
            P += dlt;
            float du = dlt * ruv[k];
            float psum = 0.f;
#pragma unroll
            for (int j = 0; j < 4; ++j) {
                float e = __expf(fmaf(-Af[j], P, Sb[j]));
                num[j] = fmaf(du * Bq[k][j], e, num[j]);
                float rr = __builtin_amdgcn_rcpf(e + 1e-12f);
                psum = fmaf(num[j] * rr, Cq[k][j], psum);
            }
            psum += __shfl_xor(psum, 1);
            psum += __shfl_xor(psum, 2);
            if (l == 0) syp[c * 17 + t4 * 4 + k] = fmaf(ruv[k], Dv, psum);
        }
    }
    __syncthreads();
    {
        int cc = tid >> 2, oo = (tid & 3) * 4;
        const float* sp = &syp[cc * 17 + oo];
        ushort4 o;
        o.x = f2bf(sp[0]);
        o.y = f2bf(sp[1]);
        o.z = f2bf(sp[2]);
        o.w = f2bf(sp[3]);
        *reinterpret_cast<ushort4*>(&yTbf[(size_t)d * MTOT + m0 + tid * 4]) = o;
    }
}

// ---------------- yTbf [d][m] bf16 -> ybf [m][d] bf16 ----------------
__global__ __launch_bounds__(256) void k_ytr(const unsigned short* __restrict__ in,
                                             unsigned short* __restrict__ out) {
    __shared__ unsigned short t[64][66];
    int d0 = blockIdx.y * 64, m0 = blockIdx.x * 64;
    int tx = threadIdx.x & 63, ty = threadIdx.x >> 6;
#pragma unroll
    for (int j = 0; j < 64; j += 4)
        t[ty + j][tx] = in[(size_t)(d0 + ty + j) * MTOT + m0 + tx];
    __syncthreads();
#pragma unroll
    for (int j = 0; j < 64; j += 4)
        out[(size_t)(m0 + ty + j) * 1024 + d0 + tx] = t[tx][ty + j];
}

// ---------------- Kernel D: out = ybf @ WbfT^T + b_out via MFMA (T2-swizzled LDS) ----------------
__global__ __launch_bounds__(256) void k_gemm(const unsigned short* __restrict__ A,
                                              const unsigned short* __restrict__ B,
                                              const float* __restrict__ bias,
                                              float* __restrict__ out) {
    __shared__ unsigned short As[128 * 64];
    __shared__ unsigned short Bs[64 * 64];
    const int GN = 1024, GK = 1024;
    int bm = blockIdx.y * 128;
    int bn = blockIdx.x * 64;
    int tid = threadIdx.x;
    int lane = tid & 63;
    int w = tid >> 6;
    int wm = w >> 1, wn = w & 1;
    int r = lane & 15, kb = lane >> 4;

    f32x4 zero4 = {0.f, 0.f, 0.f, 0.f};
    f32x4 acc[4][2];
#pragma unroll
    for (int mf = 0; mf < 4; ++mf)
#pragma unroll
        for (int nf = 0; nf < 2; ++nf) acc[mf][nf] = zero4;

    s16x8 ra[4], rb[2];
    auto stage_load = [&](int k0) {
#pragma unroll
        for (int i = 0; i < 4; ++i) {
            int q = tid + i * 256;
            ra[i] = *reinterpret_cast<const s16x8*>(&A[(size_t)(bm + (q >> 3)) * GK + k0 + (q & 7) * 8]);
        }
#pragma unroll
        for (int i = 0; i < 2; ++i) {
            int q = tid + i * 256;
            rb[i] = *reinterpret_cast<const s16x8*>(&B[(size_t)(bn + (q >> 3)) * GK + k0 + (q & 7) * 8]);
        }
    };

    stage_load(0);
    for (int k0 = 0; k0 < GK; k0 += 64) {
        __syncthreads();
#pragma unroll
        for (int i = 0; i < 4; ++i) {
            int q = tid + i * 256;
            int row = q >> 3;
            int dstB = row * 128 + (((q & 7) * 16) ^ ((row & 7) << 4));
            *(s16x8*)((char*)As + dstB) = ra[i];
        }
#pragma unroll
        for (int i = 0; i < 2; ++i) {
            int q = tid + i * 256;
            int row = q >> 3;
            int dstB = row * 128 + (((q & 7) * 16) ^ ((row & 7) << 4));
            *(s16x8*)((char*)Bs + dstB) = rb[i];
        }
        __syncthreads();
        if (k0 + 64 < GK) stage_load(k0 + 64);
#pragma unroll
        for (int ks = 0; ks < 2; ++ks) {
            int sw = (ks * 64 + kb * 16) ^ ((r & 7) << 4);
            s16x8 af[4], bfr[2];
#pragma unroll
            for (int mf = 0; mf < 4; ++mf)
                af[mf] = *(const s16x8*)((char*)As + (wm * 64 + mf * 16 + r) * 128 + sw);
#pragma unroll
            for (int nf = 0; nf < 2; ++nf)
                bfr[nf] = *(const s16x8*)((char*)Bs + (wn * 32 + nf * 16 + r) * 128 + sw);
#pragma unroll
            for (int mf = 0; mf < 4; ++mf)
#pragma unroll
                for (int nf = 0; nf < 2; ++nf)
                    acc[mf][nf] = __builtin_amdgcn_mfma_f32_16x16x32_bf16(af[mf], bfr[nf], acc[mf][nf], 0, 0, 0);
        }
    }
#pragma unroll
    for (int nf = 0; nf < 2; ++nf) {
        float bb = bias[bn + wn * 32 + nf * 16 + r];
#pragma unroll
        for (int mf = 0; mf < 4; ++mf)
#pragma unroll
            for (int j = 0; j < 4; ++j)
                out[(size_t)(bm + wm * 64 + mf * 16 + kb * 4 + j) * GN + bn + wn * 32 + nf * 16 + r] =
                    acc[mf][nf][j] + bb;
    }
}

extern "C" void kernel_launch(void* const* d_in, const int* in_sizes, int n_in,
                              void* d_out, int out_size, void* d_ws, size_t ws_size,
                              hipStream_t stream) {
    const float* x    = (const float*)d_in[0];
    const float* Wx   = (const float*)d_in[1];
    const float* Wdt  = (const float*)d_in[2];
    const float* bdt  = (const float*)d_in[3];
    const float* Alog = (const float*)d_in[4];
    const float* Dp   = (const float*)d_in[5];
    const float* Wout = (const float*)d_in[6];
    const float* bout = (const float*)d_in[7];
    float* out = (float*)d_out;

    float* xT     = (float*)d_ws;                          // 1024*2048 f
    float* deltaT = xT + 1024 * 2048;                      // 1024*2048 f
    float* bpk    = deltaT + 1024 * 2048;                  // 2048*16 f
    float* cpk    = bpk + 2048 * 16;                       // 2048*16 f
    float* part   = cpk + 2048 * 16;                       // 4*2048*96 f
    unsigned short* xh    = (unsigned short*)(part + 4 * 2048 * 96);
    unsigned short* xl    = xh + 2048 * 1024;
    unsigned short* WxTh  = xl + 2048 * 1024;              // 96*1024
    unsigned short* WxTl  = WxTh + 96 * 1024;
    unsigned short* WdtTh = WxTl + 96 * 1024;              // 1024*64
    unsigned short* WdtTl = WdtTh + 1024 * 64;
    unsigned short* xdh   = WdtTl + 1024 * 64;             // 2048*64
    unsigned short* xdl   = xdh + 2048 * 64;
    unsigned short* yTbf  = xdl + 2048 * 64;               // 1024*2048
    unsigned short* ybf   = yTbf + 1024 * 2048;            // 2048*1024
    unsigned short* WbfT  = ybf + 2048 * 1024;             // 1024*1024

    k_prep<<<928, 256, 0, stream>>>(x, Wx, Wdt, Wout, xT, xh, xl,
                                    WxTh, WxTl, WdtTh, WdtTl, WbfT);
    k_xdbl3<<<256, 256, 0, stream>>>(xh, xl, WxTh, WxTl, part);
    k_xred<<<192, 256, 0, stream>>>(part, xdh, xdl, bpk, cpk);
    k_delta2<<<dim3(8, 16), 256, 0, stream>>>(xdh, xdl, WdtTh, WdtTl, bdt, deltaT);
    k_scan3<<<2048, 256, 0, stream>>>(deltaT, xT, bpk, cpk, Alog, Dp, yTbf);
    k_ytr<<<dim3(32, 16), 256, 0, stream>>>(yTbf, ybf);
    k_gemm<<<dim3(16, 16), 256, 0, stream>>>(ybf, WbfT, bout, out);
}

// Round 8
// 72.126 us; speedup vs baseline: 2.0951x; 1.1240x over previous
//
#include <hip/hip_runtime.h>
#include <hip/hip_bf16.h>

// b=2, L=1024, d=1024, dt_rank=64, n=16, E=96
#define LSEQ 1024
#define DMODEL 1024
#define NSTATE 16
#define DTRANK 64
#define ECOL 96
#define MTOT 2048

typedef short s16x8 __attribute__((ext_vector_type(8)));
typedef float f32x4 __attribute__((ext_vector_type(4)));

__device__ inline unsigned short f2bf(float f) {
    unsigned int u = __builtin_bit_cast(unsigned int, f);
    u += 0x7FFFu + ((u >> 16) & 1u);
    return (unsigned short)(u >> 16);
}
__device__ inline float bf2f(unsigned short h) {
    unsigned int u = ((unsigned int)h) << 16;
    return __builtin_bit_cast(float, u);
}

__device__ inline f32x4 shflup4(f32x4 v, int off) {
    f32x4 r;
    r[0] = __shfl_up(v[0], off, 64);
    r[1] = __shfl_up(v[1], off, 64);
    r[2] = __shfl_up(v[2], off, 64);
    r[3] = __shfl_up(v[3], off, 64);
    return r;
}

// ---------------- fused prep: x->{xT,xh,xl}, Wx->WxT h/l, Wdt->WdtT h/l, Wout->WbfT ----------------
__global__ __launch_bounds__(256) void k_prep(const float* __restrict__ x,
                                              const float* __restrict__ Wx,
                                              const float* __restrict__ Wdt,
                                              const float* __restrict__ Wout,
                                              float* __restrict__ xT,
                                              unsigned short* __restrict__ xh,
                                              unsigned short* __restrict__ xl,
                                              unsigned short* __restrict__ WxTh,
                                              unsigned short* __restrict__ WxTl,
                                              unsigned short* __restrict__ WdtTh,
                                              unsigned short* __restrict__ WdtTl,
                                              unsigned short* __restrict__ WbfT) {
    __shared__ float t[64][65];
    int id = blockIdx.x;
    int tid = threadIdx.x;
    if (id < 512) {
        int d0 = (id & 15) * 64, m0 = (id >> 4) * 64;
        int tx = tid & 63, ty = tid >> 6;
#pragma unroll
        for (int j = 0; j < 64; j += 4) {
            size_t src = (size_t)(m0 + ty + j) * 1024 + d0 + tx;
            float v = x[src];
            t[ty + j][tx] = v;
            unsigned short h = f2bf(v);
            xh[src] = h;
            xl[src] = f2bf(v - bf2f(h));
        }
        __syncthreads();
#pragma unroll
        for (int j = 0; j < 64; j += 4)
            xT[(size_t)(d0 + ty + j) * 2048 + m0 + tx] = t[tx][ty + j];
    } else if (id < 512 + 96) {
        int id2 = id - 512;
        int e0 = (id2 % 3) * 32, k0 = (id2 / 3) * 32;
        int tx = tid & 31, ty = tid >> 5;
#pragma unroll
        for (int j = 0; j < 32; j += 8)
            t[ty + j][tx] = Wx[(size_t)(k0 + ty + j) * 96 + e0 + tx];
        __syncthreads();
#pragma unroll
        for (int j = 0; j < 32; j += 8) {
            float v = t[tx][ty + j];
            unsigned short h = f2bf(v);
            WxTh[(size_t)(e0 + ty + j) * 1024 + k0 + tx] = h;
            WxTl[(size_t)(e0 + ty + j) * 1024 + k0 + tx] = f2bf(v - bf2f(h));
        }
    } else if (id < 512 + 96 + 64) {
        int id3 = id - (512 + 96);
        int d0 = (id3 & 31) * 32, r0 = (id3 >> 5) * 32;
        int tx = tid & 31, ty = tid >> 5;
#pragma unroll
        for (int j = 0; j < 32; j += 8)
            t[ty + j][tx] = Wdt[(size_t)(r0 + ty + j) * 1024 + d0 + tx];
        __syncthreads();
#pragma unroll
        for (int j = 0; j < 32; j += 8) {
            float v = t[tx][ty + j];
            unsigned short h = f2bf(v);
            WdtTh[(size_t)(d0 + ty + j) * 64 + r0 + tx] = h;
            WdtTl[(size_t)(d0 + ty + j) * 64 + r0 + tx] = f2bf(v - bf2f(h));
        }
    } else {
        int id4 = id - (512 + 96 + 64);
        int e0 = (id4 & 15) * 64, k0 = (id4 >> 4) * 64;
        int tx = tid & 63, ty = tid >> 6;
#pragma unroll
        for (int j = 0; j < 64; j += 4)
            t[ty + j][tx] = Wout[(size_t)(k0 + ty + j) * 1024 + e0 + tx];
        __syncthreads();
#pragma unroll
        for (int j = 0; j < 64; j += 4)
            WbfT[(size_t)(e0 + ty + j) * 1024 + k0 + tx] = f2bf(t[tx][ty + j]);
    }
}

// ---------------- xdbl via MFMA split, split-K: part[slice][2048][96] ----------------
__global__ __launch_bounds__(256) void k_xdbl3(const unsigned short* __restrict__ xh,
                                               const unsigned short* __restrict__ xl,
                                               const unsigned short* __restrict__ WxTh,
                                               const unsigned short* __restrict__ WxTl,
                                               float* __restrict__ part) {
    __shared__ unsigned short Ah[32 * 64], Al[32 * 64];
    __shared__ unsigned short Bh[96 * 64], Bl[96 * 64];
    int bm = (blockIdx.x >> 2) * 32;
    int slice = blockIdx.x & 3;
    int tid = threadIdx.x, lane = tid & 63, w = tid >> 6;
    int wm = w >> 1, wn = w & 1;
    int r = lane & 15, kb = lane >> 4;

    f32x4 acc[3];
#pragma unroll
    for (int nf = 0; nf < 3; ++nf) acc[nf] = (f32x4){0.f, 0.f, 0.f, 0.f};

#pragma unroll 1
    for (int kc = 0; kc < 4; ++kc) {
        int kbase = slice * 256 + kc * 64;
        __syncthreads();
        {
            int row = tid >> 3, cc = tid & 7;
            size_t src = (size_t)(bm + row) * 1024 + kbase + cc * 8;
            int dstB = row * 128 + ((cc * 16) ^ ((row & 7) << 4));
            *(s16x8*)((char*)Ah + dstB) = *(const s16x8*)&xh[src];
            *(s16x8*)((char*)Al + dstB) = *(const s16x8*)&xl[src];
        }
#pragma unroll
        for (int j = 0; j < 3; ++j) {
            int c = tid + j * 256;
            int row = c >> 3, cc = c & 7;
            size_t src = (size_t)row * 1024 + kbase + cc * 8;
            int dstB = row * 128 + ((cc * 16) ^ ((row & 7) << 4));
            *(s16x8*)((char*)Bh + dstB) = *(const s16x8*)&WxTh[src];
            *(s16x8*)((char*)Bl + dstB) = *(const s16x8*)&WxTl[src];
        }
        __syncthreads();
#pragma unroll
        for (int ks = 0; ks < 2; ++ks) {
            int sw = (ks * 64 + kb * 16) ^ ((r & 7) << 4);
            s16x8 a_h = *(const s16x8*)((char*)Ah + (wm * 16 + r) * 128 + sw);
            s16x8 a_l = *(const s16x8*)((char*)Al + (wm * 16 + r) * 128 + sw);
#pragma unroll
            for (int nf = 0; nf < 3; ++nf) {
                int brow = wn * 48 + nf * 16 + r;
                s16x8 b_h = *(const s16x8*)((char*)Bh + brow * 128 + sw);
                s16x8 b_l = *(const s16x8*)((char*)Bl + brow * 128 + sw);
                acc[nf] = __builtin_amdgcn_mfma_f32_16x16x32_bf16(a_h, b_h, acc[nf], 0, 0, 0);
                acc[nf] = __builtin_amdgcn_mfma_f32_16x16x32_bf16(a_h, b_l, acc[nf], 0, 0, 0);
                acc[nf] = __builtin_amdgcn_mfma_f32_16x16x32_bf16(a_l, b_h, acc[nf], 0, 0, 0);
            }
        }
    }
    float* pb = part + (size_t)slice * 2048 * 96;
#pragma unroll
    for (int nf = 0; nf < 3; ++nf)
#pragma unroll
        for (int j = 0; j < 4; ++j)
            pb[(size_t)(bm + wm * 16 + kb * 4 + j) * 96 + wn * 48 + nf * 16 + r] = acc[nf][j];
}

// ---------------- delta via MFMA (fused part-reduce): M-tile 128, N-tile 64, K=64 ----------------
// phase 0: reduce 4 part-slices -> bf16 h/l A-tile in swizzled LDS (+ bpk/cpk if bn==0)
// phase 1: MFMA (A from LDS, B direct) ; phase 2: softplus + transpose -> deltaT [d][m]
__global__ __launch_bounds__(256) void k_delta2(const float* __restrict__ part,
                                                const unsigned short* __restrict__ WdtTh,
                                                const unsigned short* __restrict__ WdtTl,
                                                const float* __restrict__ bdt,
                                                float* __restrict__ deltaT,
                                                float* __restrict__ bpk,
                                                float* __restrict__ cpk) {
    __shared__ char pool[34816];  // union: Ah/Al (32KB) then slab (34KB)
    unsigned short* Ah = (unsigned short*)pool;
    unsigned short* Al = (unsigned short*)(pool + 16384);
    float (*slab)[32][68] = (float (*)[32][68])pool;

    int bm = blockIdx.y * 128;
    int bn = blockIdx.x * 64;
    int tid = threadIdx.x, lane = tid & 63, w = tid >> 6;
    int wm = w >> 1, wn = w & 1;
    int r = lane & 15, kb = lane >> 4;

    // ---- phase 0: reduce part slices for delta cols 0..63 -> LDS h/l ----
#pragma unroll
    for (int i = 0; i < 8; ++i) {
        int q = tid + i * 256;       // f32x4 slot: 128 rows x 16
        int row = q >> 4, c4 = q & 15;
        size_t off = (size_t)(bm + row) * 96 + c4 * 4;
        f32x4 v = *(const f32x4*)&part[off];
#pragma unroll
        for (int s = 1; s < 4; ++s) v += *(const f32x4*)&part[(size_t)s * 2048 * 96 + off];
        ushort4 h4, l4;
        h4.x = f2bf(v[0]); l4.x = f2bf(v[0] - bf2f(h4.x));
        h4.y = f2bf(v[1]); l4.y = f2bf(v[1] - bf2f(h4.y));
        h4.z = f2bf(v[2]); l4.z = f2bf(v[2] - bf2f(h4.z));
        h4.w = f2bf(v[3]); l4.w = f2bf(v[3] - bf2f(h4.w));
        int dstB = row * 128 + ((c4 * 8) ^ ((row & 7) << 4));
        *(ushort4*)((char*)Ah + dstB) = h4;
        *(ushort4*)((char*)Al + dstB) = l4;
    }
    if (blockIdx.x == 0) {  // B/C packed outputs (cols 64..95)
#pragma unroll
        for (int i = 0; i < 4; ++i) {
            int q = tid + i * 256;   // 128 rows x 8 f32x4
            int row = q >> 3, c4 = q & 7;
            size_t off = (size_t)(bm + row) * 96 + 64 + c4 * 4;
            f32x4 v = *(const f32x4*)&part[off];
#pragma unroll
            for (int s = 1; s < 4; ++s) v += *(const f32x4*)&part[(size_t)s * 2048 * 96 + off];
            if (c4 < 4) *(f32x4*)&bpk[(size_t)(bm + row) * 16 + c4 * 4] = v;
            else        *(f32x4*)&cpk[(size_t)(bm + row) * 16 + (c4 - 4) * 4] = v;
        }
    }
    __syncthreads();

    // ---- phase 1: MFMA ----
    f32x4 acc[4][2];
#pragma unroll
    for (int mf = 0; mf < 4; ++mf)
#pragma unroll
        for (int nf = 0; nf < 2; ++nf) acc[mf][nf] = (f32x4){0.f, 0.f, 0.f, 0.f};

#pragma unroll
    for (int ks = 0; ks < 2; ++ks) {
        int sw = (ks * 64 + kb * 16) ^ ((r & 7) << 4);
        s16x8 Afh[4], Afl[4], Bh[2], Bl[2];
#pragma unroll
        for (int mf = 0; mf < 4; ++mf) {
            int arow = wm * 64 + mf * 16 + r;
            Afh[mf] = *(const s16x8*)((char*)Ah + arow * 128 + sw);
            Afl[mf] = *(const s16x8*)((char*)Al + arow * 128 + sw);
        }
#pragma unroll
        for (int nf = 0; nf < 2; ++nf) {
            size_t b = (size_t)(bn + wn * 32 + nf * 16 + r) * 64 + ks * 32 + kb * 8;
            Bh[nf] = *(const s16x8*)&WdtTh[b];
            Bl[nf] = *(const s16x8*)&WdtTl[b];
        }
#pragma unroll
        for (int mf = 0; mf < 4; ++mf)
#pragma unroll
            for (int nf = 0; nf < 2; ++nf) {
                acc[mf][nf] = __builtin_amdgcn_mfma_f32_16x16x32_bf16(Afh[mf], Bh[nf], acc[mf][nf], 0, 0, 0);
                acc[mf][nf] = __builtin_amdgcn_mfma_f32_16x16x32_bf16(Afh[mf], Bl[nf], acc[mf][nf], 0, 0, 0);
                acc[mf][nf] = __builtin_amdgcn_mfma_f32_16x16x32_bf16(Afl[mf], Bh[nf], acc[mf][nf], 0, 0, 0);
            }
    }
    __syncthreads();  // all waves done reading Ah/Al before slab overlays pool

    // ---- phase 2: softplus + per-wave transpose -> deltaT [d][m] ----
#pragma unroll
    for (int nf = 0; nf < 2; ++nf) {
        float bb = bdt[bn + wn * 32 + nf * 16 + r];
#pragma unroll
        for (int mf = 0; mf < 4; ++mf)
#pragma unroll
            for (int j = 0; j < 4; ++j) {
                float z = acc[mf][nf][j] + bb;
                float sp = fmaxf(z, 0.f) + log1pf(expf(-fabsf(z)));
                slab[w][nf * 16 + r][mf * 16 + kb * 4 + j] = sp;
            }
    }
#pragma unroll
    for (int i = 0; i < 8; ++i) {
        int idx = i * 64 + lane;
        int dl = idx >> 4, mq = (idx & 15) * 4;
        f32x4 v = *(const f32x4*)&slab[w][dl][mq];
        *(f32x4*)&deltaT[(size_t)(bn + wn * 32 + dl) * MTOT + bm + wm * 64 + mq] = v;
    }
}

// ---------------- Kernel C: chunked selective scan -> yT bf16 [d][m] ----------------
__global__ __launch_bounds__(256) void k_scan3(const float* __restrict__ deltaT,
                                               const float* __restrict__ xT,
                                               const float* __restrict__ bpk,
                                               const float* __restrict__ cpk,
                                               const float* __restrict__ Alog,
                                               const float* __restrict__ Dp,
                                               unsigned short* __restrict__ yTbf) {
    __shared__ double csum[64];
    __shared__ double Rbef[64];
    __shared__ float TcL[64 * 20];
    __shared__ float syp[64 * 17];

    int tid = threadIdx.x;
    int c = tid >> 2, l = tid & 3;
    int w = tid >> 6, lane = tid & 63;
    int d = blockIdx.x & 1023, b = blockIdx.x >> 10;
    int m0 = b * 1024;

    const f32x4* dp = (const f32x4*)(deltaT + (size_t)d * MTOT + m0 + c * 16);
    const f32x4* up = (const f32x4*)(xT + (size_t)d * MTOT + m0 + c * 16);
    const f32x4* Bp = (const f32x4*)bpk + (size_t)(m0 + c * 16) * 4 + l;
    const f32x4* Cp = (const f32x4*)cpk + (size_t)(m0 + c * 16) * 4 + l;

    double dsum = 0.0;
#pragma unroll
    for (int i = 0; i < 4; ++i) {
        f32x4 v = dp[i];
        dsum += (double)v[0] + (double)v[1] + (double)v[2] + (double)v[3];
    }
    if (l == 0) csum[c] = dsum;
    __syncthreads();
    if (tid < 64) {
        double v = csum[tid];
#pragma unroll
        for (int off = 1; off < 64; off <<= 1) {
            double t = __shfl_down(v, off, 64);
            if (tid + off < 64) v += t;
        }
        Rbef[tid] = v;
    }
    __syncthreads();

    float Af[4], Sb[4];
    double Rb = Rbef[c];
#pragma unroll
    for (int j = 0; j < 4; ++j) {
        Af[j] = -__expf(Alog[d * NSTATE + 4 * l + j]);
        Sb[j] = (float)((double)Af[j] * Rb);
    }
    float Dv = Dp[d];

    float P = 0.f;
    f32x4 Tn = {0.f, 0.f, 0.f, 0.f};
#pragma unroll 1
    for (int t4 = 0; t4 < 4; ++t4) {
        f32x4 rdv = dp[t4];
        f32x4 ruv = up[t4];
        f32x4 Bq0 = Bp[(t4 * 4 + 0) * 4];
        f32x4 Bq1 = Bp[(t4 * 4 + 1) * 4];
        f32x4 Bq2 = Bp[(t4 * 4 + 2) * 4];
        f32x4 Bq3 = Bp[(t4 * 4 + 3) * 4];
        f32x4 Bq[4] = {Bq0, Bq1, Bq2, Bq3};
#pragma unroll
        for (int k = 0; k < 4; ++k) {
            float dlt = rdv[k];
            P += dlt;
            float du = dlt * ruv[k];
#pragma unroll
            for (int j = 0; j < 4; ++j) {
                float e = __expf(fmaf(-Af[j], P, Sb[j]));
                Tn[j] = fmaf(du * Bq[k][j], e, Tn[j]);
            }
        }
    }
    *(f32x4*)&TcL[c * 20 + 4 * l] = Tn;
    __syncthreads();

    {
        f32x4 v = *(const f32x4*)&TcL[lane * 20 + 4 * w];
#pragma unroll
        for (int off = 1; off < 64; off <<= 1) {
            f32x4 t = shflup4(v, off);
            if (lane >= off) v += t;
        }
        f32x4 ex = shflup4(v, 1);
        if (lane == 0) ex = (f32x4){0.f, 0.f, 0.f, 0.f};
        *(f32x4*)&TcL[lane * 20 + 4 * w] = ex;
    }
    __syncthreads();
    f32x4 num = *(const f32x4*)&TcL[c * 20 + 4 * l];

    P = 0.f;
#pragma unroll 1
    for (int t4 = 0; t4 < 4; ++t4) {
        f32x4 rdv = dp[t4];
        f32x4 ruv = up[t4];
        f32x4 Bq[4], Cq[4];
#pragma unroll
        for (int k = 0; k < 4; ++k) {
            Bq[k] = Bp[(t4 * 4 + k) * 4];
            Cq[k] = Cp[(t4 * 4 + k) * 4];
        }
#pragma unroll
        for (int k = 0; k < 4; ++k) {
            float dlt = rdv[k];
            P += dlt;
            float du = dlt * ruv[k];
            float psum = 0.f;
#pragma unroll
            for (int j = 0; j < 4; ++j) {
                float e = __expf(fmaf(-Af[j], P, Sb[j]));
                num[j] = fmaf(du * Bq[k][j], e, num[j]);
                float rr = __builtin_amdgcn_rcpf(e + 1e-12f);
                psum = fmaf(num[j] * rr, Cq[k][j], psum);
            }
            psum += __shfl_xor(psum, 1);
            psum += __shfl_xor(psum, 2);
            if (l == 0) syp[c * 17 + t4 * 4 + k] = fmaf(ruv[k], Dv, psum);
        }
    }
    __syncthreads();
    {
        int cc = tid >> 2, oo = (tid & 3) * 4;
        const float* sp = &syp[cc * 17 + oo];
        ushort4 o;
        o.x = f2bf(sp[0]);
        o.y = f2bf(sp[1]);
        o.z = f2bf(sp[2]);
        o.w = f2bf(sp[3]);
        *reinterpret_cast<ushort4*>(&yTbf[(size_t)d * MTOT + m0 + tid * 4]) = o;
    }
}

// ---------------- yTbf [d][m] bf16 -> ybf [m][d] bf16 ----------------
__global__ __launch_bounds__(256) void k_ytr(const unsigned short* __restrict__ in,
                                             unsigned short* __restrict__ out) {
    __shared__ unsigned short t[64][66];
    int d0 = blockIdx.y * 64, m0 = blockIdx.x * 64;
    int tx = threadIdx.x & 63, ty = threadIdx.x >> 6;
#pragma unroll
    for (int j = 0; j < 64; j += 4)
        t[ty + j][tx] = in[(size_t)(d0 + ty + j) * MTOT + m0 + tx];
    __syncthreads();
#pragma unroll
    for (int j = 0; j < 64; j += 4)
        out[(size_t)(m0 + ty + j) * 1024 + d0 + tx] = t[tx][ty + j];
}

// ---------------- Kernel D: out = ybf @ WbfT^T + b_out via MFMA, BM=64, grid 512 ----------------
__global__ __launch_bounds__(256) void k_gemm(const unsigned short* __restrict__ A,
                                              const unsigned short* __restrict__ B,
                                              const float* __restrict__ bias,
                                              float* __restrict__ out) {
    __shared__ unsigned short As[64 * 64];
    __shared__ unsigned short Bs[64 * 64];
    const int GN = 1024, GK = 1024;
    int bm = blockIdx.y * 64;
    int bn = blockIdx.x * 64;
    int tid = threadIdx.x;
    int lane = tid & 63;
    int w = tid >> 6;
    int wm = w >> 1, wn = w & 1;
    int r = lane & 15, kb = lane >> 4;

    f32x4 acc[2][2];
#pragma unroll
    for (int mf = 0; mf < 2; ++mf)
#pragma unroll
        for (int nf = 0; nf < 2; ++nf) acc[mf][nf] = (f32x4){0.f, 0.f, 0.f, 0.f};

    s16x8 ra[2], rb[2];
    auto stage_load = [&](int k0) {
#pragma unroll
        for (int i = 0; i < 2; ++i) {
            int q = tid + i * 256;
            ra[i] = *reinterpret_cast<const s16x8*>(&A[(size_t)(bm + (q >> 3)) * GK + k0 + (q & 7) * 8]);
            rb[i] = *reinterpret_cast<const s16x8*>(&B[(size_t)(bn + (q >> 3)) * GK + k0 + (q & 7) * 8]);
        }
    };

    stage_load(0);
    for (int k0 = 0; k0 < GK; k0 += 64) {
        __syncthreads();
#pragma unroll
        for (int i = 0; i < 2; ++i) {
            int q = tid + i * 256;
            int row = q >> 3;
            int dstB = row * 128 + (((q & 7) * 16) ^ ((row & 7) << 4));
            *(s16x8*)((char*)As + dstB) = ra[i];
            *(s16x8*)((char*)Bs + dstB) = rb[i];
        }
        __syncthreads();
        if (k0 + 64 < GK) stage_load(k0 + 64);
#pragma unroll
        for (int ks = 0; ks < 2; ++ks) {
            int sw = (ks * 64 + kb * 16) ^ ((r & 7) << 4);
            s16x8 af[2], bfr[2];
#pragma unroll
            for (int mf = 0; mf < 2; ++mf)
                af[mf] = *(const s16x8*)((char*)As + (wm * 32 + mf * 16 + r) * 128 + sw);
#pragma unroll
            for (int nf = 0; nf < 2; ++nf)
                bfr[nf] = *(const s16x8*)((char*)Bs + (wn * 32 + nf * 16 + r) * 128 + sw);
#pragma unroll
            for (int mf = 0; mf < 2; ++mf)
#pragma unroll
                for (int nf = 0; nf < 2; ++nf)
                    acc[mf][nf] = __builtin_amdgcn_mfma_f32_16x16x32_bf16(af[mf], bfr[nf], acc[mf][nf], 0, 0, 0);
        }
    }
#pragma unroll
    for (int nf = 0; nf < 2; ++nf) {
        float bb = bias[bn + wn * 32 + nf * 16 + r];
#pragma unroll
        for (int mf = 0; mf < 2; ++mf)
#pragma unroll
            for (int j = 0; j < 4; ++j)
                out[(size_t)(bm + wm * 32 + mf * 16 + kb * 4 + j) * GN + bn + wn * 32 + nf * 16 + r] =
                    acc[mf][nf][j] + bb;
    }
}

extern "C" void kernel_launch(void* const* d_in, const int* in_sizes, int n_in,
                              void* d_out, int out_size, void* d_ws, size_t ws_size,
                              hipStream_t stream) {
    const float* x    = (const float*)d_in[0];
    const float* Wx   = (const float*)d_in[1];
    const float* Wdt  = (const float*)d_in[2];
    const float* bdt  = (const float*)d_in[3];
    const float* Alog = (const float*)d_in[4];
    const float* Dp   = (const float*)d_in[5];
    const float* Wout = (const float*)d_in[6];
    const float* bout = (const float*)d_in[7];
    float* out = (float*)d_out;

    float* xT     = (float*)d_ws;                          // 1024*2048 f
    float* deltaT = xT + 1024 * 2048;                      // 1024*2048 f
    float* bpk    = deltaT + 1024 * 2048;                  // 2048*16 f
    float* cpk    = bpk + 2048 * 16;                       // 2048*16 f
    float* part   = cpk + 2048 * 16;                       // 4*2048*96 f
    unsigned short* xh    = (unsigned short*)(part + 4 * 2048 * 96);
    unsigned short* xl    = xh + 2048 * 1024;
    unsigned short* WxTh  = xl + 2048 * 1024;              // 96*1024
    unsigned short* WxTl  = WxTh + 96 * 1024;
    unsigned short* WdtTh = WxTl + 96 * 1024;              // 1024*64
    unsigned short* WdtTl = WdtTh + 1024 * 64;
    unsigned short* yTbf  = WdtTl + 1024 * 64;             // 1024*2048
    unsigned short* ybf   = yTbf + 1024 * 2048;            // 2048*1024
    unsigned short* WbfT  = ybf + 2048 * 1024;             // 1024*1024

    k_prep<<<928, 256, 0, stream>>>(x, Wx, Wdt, Wout, xT, xh, xl,
                                    WxTh, WxTl, WdtTh, WdtTl, WbfT);
    k_xdbl3<<<256, 256, 0, stream>>>(xh, xl, WxTh, WxTl, part);
    k_delta2<<<dim3(16, 16), 256, 0, stream>>>(part, WdtTh, WdtTl, bdt, deltaT, bpk, cpk);
    k_scan3<<<2048, 256, 0, stream>>>(deltaT, xT, bpk, cpk, Alog, Dp, yTbf);
    k_ytr<<<dim3(32, 16), 256, 0, stream>>>(yTbf, ybf);
    k_gemm<<<dim3(16, 32), 256, 0, stream>>>(ybf, WbfT, bout, out);
}